// Round 1
// baseline (2479.794 us; speedup 1.0000x reference)
//
#include <hip/hip_runtime.h>

// ---------------------------------------------------------------------------
// 2-layer hetero GraphSAGE (user<->movie) + dot-product link head.
// Round 1: correctness-first. Aggregation via fp32 atomics (wave-per-edge),
// apply via wave-per-node matvec with LDS-staged weights (pitch 65, conflict
// free). All buffers in d_ws; layer-0 user features alias user_emb input.
// ---------------------------------------------------------------------------

__global__ void deg_kernel(const int* __restrict__ src, const int* __restrict__ dst,
                           float* __restrict__ deg_u, float* __restrict__ deg_m, int E) {
    int e = blockIdx.x * blockDim.x + threadIdx.x;
    if (e < E) {
        atomicAdd(&deg_u[src[e]], 1.0f);
        atomicAdd(&deg_m[dst[e]], 1.0f);
    }
}

// x_m = movie_x @ movie_lin_w.T + movie_lin_b + movie_emb   [M,64]
__global__ void movie_init_kernel(const float* __restrict__ movie_x,  // [M,20]
                                  const float* __restrict__ wm,       // [64,20]
                                  const float* __restrict__ bm,       // [64]
                                  const float* __restrict__ memb,     // [M,64]
                                  float* __restrict__ xm, int M) {
    __shared__ float w_s[64 * 21];
    int lane = threadIdx.x & 63;
    for (int i = threadIdx.x; i < 64 * 20; i += blockDim.x) {
        int h = i / 20, f = i % 20;
        w_s[h * 21 + f] = wm[i];
    }
    __syncthreads();
    float bias = bm[lane];
    int nw = (gridDim.x * blockDim.x) >> 6;
    int w  = (blockIdx.x * blockDim.x + threadIdx.x) >> 6;
    for (int m = w; m < M; m += nw) {
        float fv  = (lane < 20) ? movie_x[m * 20 + lane] : 0.0f;
        float acc = bias + memb[m * 64 + lane];
#pragma unroll
        for (int f = 0; f < 20; ++f) {
            float xv = __shfl(fv, f, 64);
            acc += xv * w_s[lane * 21 + f];
        }
        xm[m * 64 + lane] = acc;
    }
}

// One pass over edges serves both directions: gather x_u[src] -> agg_m[dst],
// gather x_m[dst] -> agg_u[src]. Wave-per-edge, lane = feature index.
__global__ void agg_kernel(const int* __restrict__ src, const int* __restrict__ dst,
                           const float* __restrict__ xu, const float* __restrict__ xm,
                           float* __restrict__ agg_m, float* __restrict__ agg_u, int E) {
    int lane = threadIdx.x & 63;
    int nw = (gridDim.x * blockDim.x) >> 6;
    int w  = (blockIdx.x * blockDim.x + threadIdx.x) >> 6;
    for (int e = w; e < E; e += nw) {
        int s = src[e], d = dst[e];
        float vu = xu[(size_t)s * 64 + lane];
        float vm = xm[(size_t)d * 64 + lane];
        atomicAdd(&agg_m[(size_t)d * 64 + lane], vu);
        atomicAdd(&agg_u[(size_t)s * 64 + lane], vm);
    }
}

// out[i][h] = relu?( sum_k (agg[i][k]/max(deg,1)) * wl[h][k] + bl[h]
//                  + sum_k xold[i][k] * wr[h][k] )
// Written in place over agg. Wave-per-node; weights in LDS (pitch 65 ->
// bank=(h+k)%32, 2-way aliasing = free). Row values broadcast via __shfl.
__global__ void apply_kernel(float* __restrict__ agg,        // [n,64] in/out
                             const float* __restrict__ xold, // [n,64]
                             const float* __restrict__ deg,  // [n]
                             const float* __restrict__ wl,   // [64,64]
                             const float* __restrict__ bl,   // [64]
                             const float* __restrict__ wr,   // [64,64]
                             int n, int do_relu) {
    __shared__ float wl_s[64 * 65];
    __shared__ float wr_s[64 * 65];
    int lane = threadIdx.x & 63;
    for (int i = threadIdx.x; i < 64 * 64; i += blockDim.x) {
        int h = i >> 6, k = i & 63;
        wl_s[h * 65 + k] = wl[i];
        wr_s[h * 65 + k] = wr[i];
    }
    __syncthreads();
    float bias = bl[lane];
    int nw = (gridDim.x * blockDim.x) >> 6;
    int w  = (blockIdx.x * blockDim.x + threadIdx.x) >> 6;
    for (int i = w; i < n; i += nw) {
        float inv  = 1.0f / fmaxf(deg[i], 1.0f);
        float mean = agg[(size_t)i * 64 + lane] * inv;
        float bv   = xold[(size_t)i * 64 + lane];
        float acc  = bias;
#pragma unroll
        for (int k = 0; k < 64; ++k) {
            acc += __shfl(mean, k, 64) * wl_s[lane * 65 + k];
            acc += __shfl(bv,   k, 64) * wr_s[lane * 65 + k];
        }
        if (do_relu) acc = fmaxf(acc, 0.0f);
        agg[(size_t)i * 64 + lane] = acc;
    }
}

// out[e] = dot(x_u[label_src[e]], x_m[label_dst[e]])
__global__ void dot_kernel(const int* __restrict__ ls, const int* __restrict__ ld,
                           const float* __restrict__ xu, const float* __restrict__ xm,
                           float* __restrict__ out, int L) {
    int lane = threadIdx.x & 63;
    int nw = (gridDim.x * blockDim.x) >> 6;
    int w  = (blockIdx.x * blockDim.x + threadIdx.x) >> 6;
    for (int e = w; e < L; e += nw) {
        int u = ls[e], m = ld[e];
        float p = xu[(size_t)u * 64 + lane] * xm[(size_t)m * 64 + lane];
#pragma unroll
        for (int off = 32; off; off >>= 1) p += __shfl_down(p, off, 64);
        if (lane == 0) out[e] = p;
    }
}

extern "C" void kernel_launch(void* const* d_in, const int* in_sizes, int n_in,
                              void* d_out, int out_size, void* d_ws, size_t ws_size,
                              hipStream_t stream) {
    const float* movie_x   = (const float*)d_in[0];
    const float* user_emb  = (const float*)d_in[1];
    const float* movie_emb = (const float*)d_in[2];
    const float* mlw       = (const float*)d_in[3];
    const float* mlb       = (const float*)d_in[4];
    const float* llw       = (const float*)d_in[5];   // [2][2][64][64]
    const float* llb       = (const float*)d_in[6];   // [2][2][64]
    const float* lrw       = (const float*)d_in[7];   // [2][2][64][64]
    const int*   esrc      = (const int*)d_in[8];
    const int*   edst      = (const int*)d_in[9];
    const int*   lsrc      = (const int*)d_in[10];
    const int*   ldst      = (const int*)d_in[11];

    const int U = in_sizes[1] / 64;
    const int M = in_sizes[2] / 64;
    const int E = in_sizes[8];
    const int L = in_sizes[10];
    float* out = (float*)d_out;

    // ws layout: [x_u_b | x_m_b | deg_u | deg_m | x_u_a | x_m_a]
    float* ws    = (float*)d_ws;
    float* x_u_b = ws;
    float* x_m_b = x_u_b + (size_t)U * 64;
    float* deg_u = x_m_b + (size_t)M * 64;
    float* deg_m = deg_u + U;
    float* x_u_a = deg_m + M;
    float* x_m_a = x_u_a + (size_t)U * 64;

    // Zero layer-0 agg buffers + degree counters (contiguous region).
    size_t z1 = ((size_t)U * 64 + (size_t)M * 64 + U + M) * sizeof(float);
    hipMemsetAsync(ws, 0, z1, stream);

    deg_kernel<<<(E + 255) / 256, 256, 0, stream>>>(esrc, edst, deg_u, deg_m, E);
    movie_init_kernel<<<1024, 256, 0, stream>>>(movie_x, mlw, mlb, movie_emb, x_m_a, M);

    // ---- layer 0 ----
    agg_kernel<<<2048, 256, 0, stream>>>(esrc, edst, user_emb, x_m_a, x_m_b, x_u_b, E);
    // movies: weights [0,0]; users: weights [0,1]
    apply_kernel<<<1024, 256, 0, stream>>>(x_m_b, x_m_a, deg_m,
                                           llw + 0 * 4096, llb + 0 * 64, lrw + 0 * 4096,
                                           M, 1);
    apply_kernel<<<1024, 256, 0, stream>>>(x_u_b, user_emb, deg_u,
                                           llw + 1 * 4096, llb + 1 * 64, lrw + 1 * 4096,
                                           U, 1);

    // Zero layer-1 agg buffers (x_u_a | x_m_a contiguous). Stream-ordered
    // after layer-0 consumers of x_m_a.
    size_t z2 = ((size_t)U * 64 + (size_t)M * 64) * sizeof(float);
    hipMemsetAsync(x_u_a, 0, z2, stream);

    // ---- layer 1 ----
    agg_kernel<<<2048, 256, 0, stream>>>(esrc, edst, x_u_b, x_m_b, x_m_a, x_u_a, E);
    // movies: weights [1,0]; users: weights [1,1]
    apply_kernel<<<1024, 256, 0, stream>>>(x_m_a, x_m_b, deg_m,
                                           llw + 2 * 4096, llb + 2 * 64, lrw + 2 * 4096,
                                           M, 0);
    apply_kernel<<<1024, 256, 0, stream>>>(x_u_a, x_u_b, deg_u,
                                           llw + 3 * 4096, llb + 3 * 64, lrw + 3 * 4096,
                                           U, 0);

    // ---- link head ----
    dot_kernel<<<2048, 256, 0, stream>>>(lsrc, ldst, x_u_a, x_m_a, out, L);
}

// Round 2
// 1678.637 us; speedup vs baseline: 1.4773x; 1.4773x over previous
//
#include <hip/hip_runtime.h>

// ---------------------------------------------------------------------------
// Round 2: CSR-gather aggregation (no float atomics) + fused register-tiled
// GEMM apply. Per call: histogram -> hierarchical exclusive scan -> bucket
// scatter builds CSR for both edge directions; then 4 fused SAGE kernels
// (gather mean into LDS, 64-node x 64-out GEMM with 4x4 register tiles).
// ---------------------------------------------------------------------------

#define XP 68   // LDS pitch (multiple of 4 for float4; %32==4 -> mild conflicts ok)

// ---- CSR build ------------------------------------------------------------

__global__ void hist_kernel(const int* __restrict__ src, const int* __restrict__ dst,
                            int* __restrict__ cnt_u, int* __restrict__ cnt_m, int E) {
    int e = blockIdx.x * blockDim.x + threadIdx.x;
    if (e < E) {
        atomicAdd(&cnt_u[src[e]], 1);
        atomicAdd(&cnt_m[dst[e]], 1);
    }
}

// pass A: per-1024-chunk sums
__global__ void reduce_chunks(const int* __restrict__ cnt, int n, int* __restrict__ bsums) {
    __shared__ int red[256];
    int base = blockIdx.x * 1024;
    int s = 0;
    for (int k = 0; k < 4; ++k) {
        int i = base + k * 256 + threadIdx.x;
        if (i < n) s += cnt[i];
    }
    red[threadIdx.x] = s;
    __syncthreads();
    for (int off = 128; off; off >>= 1) {
        if (threadIdx.x < off) red[threadIdx.x] += red[threadIdx.x + off];
        __syncthreads();
    }
    if (threadIdx.x == 0) bsums[blockIdx.x] = red[0];
}

// pass B: exclusive scan of block sums (nb <= 256), single block
__global__ void scan_bsums(int* __restrict__ bsums, int nb) {
    __shared__ int s[256];
    int t = threadIdx.x;
    if (t < nb) s[t] = bsums[t];
    __syncthreads();
    if (t == 0) {
        int run = 0;
        for (int i = 0; i < nb; ++i) { int v = s[i]; s[i] = run; run += v; }
    }
    __syncthreads();
    if (t < nb) bsums[t] = s[t];
}

// pass C: per-chunk exclusive scan + block offset -> row_ptr
__global__ void scan_chunks(const int* __restrict__ cnt, int n,
                            const int* __restrict__ bsums,
                            int* __restrict__ row_ptr, int total) {
    __shared__ int sc[256];
    int t = threadIdx.x;
    int base = blockIdx.x * 1024 + t * 4;
    int4 v = make_int4(0, 0, 0, 0);
    if (base + 3 < n) v = *(const int4*)(cnt + base);
    else {
        if (base     < n) v.x = cnt[base];
        if (base + 1 < n) v.y = cnt[base + 1];
        if (base + 2 < n) v.z = cnt[base + 2];
    }
    int tsum = v.x + v.y + v.z + v.w;
    sc[t] = tsum;
    __syncthreads();
    for (int off = 1; off < 256; off <<= 1) {   // inclusive Hillis-Steele
        int val = sc[t];
        int add = (t >= off) ? sc[t - off] : 0;
        __syncthreads();
        sc[t] = val + add;
        __syncthreads();
    }
    int excl = sc[t] - tsum + bsums[blockIdx.x];
    int4 o;
    o.x = excl; o.y = o.x + v.x; o.z = o.y + v.y; o.w = o.z + v.z;
    if (base + 3 < n) *(int4*)(row_ptr + base) = o;
    else {
        if (base     < n) row_ptr[base]     = o.x;
        if (base + 1 < n) row_ptr[base + 1] = o.y;
        if (base + 2 < n) row_ptr[base + 2] = o.z;
    }
    if (blockIdx.x == 0 && t == 0) row_ptr[n] = total;
}

// bucket scatter; consumes cnt (counts down to 0)
__global__ void scatter_kernel(const int* __restrict__ src, const int* __restrict__ dst,
                               const int* __restrict__ rp_u, const int* __restrict__ rp_m,
                               int* __restrict__ cnt_u, int* __restrict__ cnt_m,
                               int* __restrict__ col_u, int* __restrict__ col_m, int E) {
    int e = blockIdx.x * blockDim.x + threadIdx.x;
    if (e < E) {
        int s = src[e], d = dst[e];
        int pu = atomicSub(&cnt_u[s], 1) - 1;
        col_u[rp_u[s] + pu] = d;
        int pm = atomicSub(&cnt_m[d], 1) - 1;
        col_m[rp_m[d] + pm] = s;
    }
}

// ---- movie feature init ---------------------------------------------------

__global__ void movie_init_kernel(const float* __restrict__ movie_x,  // [M,20]
                                  const float* __restrict__ wm,       // [64,20]
                                  const float* __restrict__ bm,       // [64]
                                  const float* __restrict__ memb,     // [M,64]
                                  float* __restrict__ xm, int M) {
    __shared__ float w_s[64 * 21];
    int lane = threadIdx.x & 63;
    for (int i = threadIdx.x; i < 64 * 20; i += blockDim.x) {
        int h = i / 20, f = i % 20;
        w_s[h * 21 + f] = wm[i];
    }
    __syncthreads();
    float bias = bm[lane];
    int nw = (gridDim.x * blockDim.x) >> 6;
    int w  = (blockIdx.x * blockDim.x + threadIdx.x) >> 6;
    for (int m = w; m < M; m += nw) {
        float fv  = (lane < 20) ? movie_x[m * 20 + lane] : 0.0f;
        float acc = bias + memb[m * 64 + lane];
#pragma unroll
        for (int f = 0; f < 20; ++f) {
            float xv = __shfl(fv, f, 64);
            acc += xv * w_s[lane * 21 + f];
        }
        xm[m * 64 + lane] = acc;
    }
}

// ---- fused SAGE: CSR gather-mean + [64n x 128k]@[128k x 64h] GEMM --------
// out[i][h] = relu?( bl[h] + sum_k mean[i][k]*wl[h][k] + sum_k self[i][k]*wr[h][k] )

__global__ __launch_bounds__(256) void sage_fused(
    const int* __restrict__ row_ptr, const int* __restrict__ col,
    const float* __restrict__ x_src,   // gather table
    const float* __restrict__ x_dst,   // self features
    const float* __restrict__ wl, const float* __restrict__ bl,
    const float* __restrict__ wr,
    float* __restrict__ out, int n, int do_relu) {
    __shared__ float Xs[128 * XP];   // [k][node], k<64: mean, k>=64: self
    __shared__ float Ws[128 * XP];   // [k][h]

    int tid = threadIdx.x;
    // stage weights transposed: Ws[m*64+k][h] = w_m[h*64+k]; global reads coalesced
    for (int i = tid; i < 8192; i += 256) {
        int m = i >> 12, rem = i & 4095, h = rem >> 6, k = rem & 63;
        const float* w = m ? wr : wl;
        Ws[(m * 64 + k) * XP + h] = w[rem];
    }

    // gather phase: 4 waves x 16 nodes
    int lane = tid & 63, wv = tid >> 6;
    int node0 = blockIdx.x * 64;
    for (int t = 0; t < 16; ++t) {
        int nl = wv * 16 + t;
        int i = node0 + nl;
        float mean = 0.0f, self = 0.0f;
        if (i < n) {
            int beg = row_ptr[i], end = row_ptr[i + 1];
            float s0 = 0.f, s1 = 0.f, s2 = 0.f, s3 = 0.f;
            int j = beg;
            for (; j + 3 < end; j += 4) {
                int c0 = col[j], c1 = col[j + 1], c2 = col[j + 2], c3 = col[j + 3];
                s0 += x_src[(size_t)c0 * 64 + lane];
                s1 += x_src[(size_t)c1 * 64 + lane];
                s2 += x_src[(size_t)c2 * 64 + lane];
                s3 += x_src[(size_t)c3 * 64 + lane];
            }
            for (; j < end; ++j) s0 += x_src[(size_t)col[j] * 64 + lane];
            float sum = (s0 + s1) + (s2 + s3);
            float inv = 1.0f / fmaxf((float)(end - beg), 1.0f);
            mean = sum * inv;
            self = x_dst[(size_t)i * 64 + lane];
        }
        Xs[lane * XP + nl]        = mean;
        Xs[(64 + lane) * XP + nl] = self;
    }
    __syncthreads();

    // GEMM phase: thread -> 4 nodes x 4 outputs
    int th = tid & 15, tn = tid >> 4;
    int n0 = tn * 4, h0 = th * 4;
    float acc[4][4];
    float4 bv = *(const float4*)&bl[h0];
#pragma unroll
    for (int r = 0; r < 4; ++r) {
        acc[r][0] = bv.x; acc[r][1] = bv.y; acc[r][2] = bv.z; acc[r][3] = bv.w;
    }
#pragma unroll 4
    for (int k = 0; k < 128; ++k) {
        float4 xv = *(const float4*)&Xs[k * XP + n0];
        float4 wv4 = *(const float4*)&Ws[k * XP + h0];
        float xr[4] = {xv.x, xv.y, xv.z, xv.w};
        float wr4[4] = {wv4.x, wv4.y, wv4.z, wv4.w};
#pragma unroll
        for (int r = 0; r < 4; ++r)
#pragma unroll
            for (int c = 0; c < 4; ++c)
                acc[r][c] += xr[r] * wr4[c];
    }
#pragma unroll
    for (int r = 0; r < 4; ++r) {
        int i = node0 + n0 + r;
        if (i < n) {
            float4 o;
            o.x = acc[r][0]; o.y = acc[r][1]; o.z = acc[r][2]; o.w = acc[r][3];
            if (do_relu) {
                o.x = fmaxf(o.x, 0.f); o.y = fmaxf(o.y, 0.f);
                o.z = fmaxf(o.z, 0.f); o.w = fmaxf(o.w, 0.f);
            }
            *(float4*)&out[(size_t)i * 64 + h0] = o;
        }
    }
}

// ---- link head ------------------------------------------------------------

__global__ void dot_kernel(const int* __restrict__ ls, const int* __restrict__ ld,
                           const float* __restrict__ xu, const float* __restrict__ xm,
                           float* __restrict__ out, int L) {
    int lane = threadIdx.x & 63;
    int nw = (gridDim.x * blockDim.x) >> 6;
    int w  = (blockIdx.x * blockDim.x + threadIdx.x) >> 6;
    for (int e = w; e < L; e += nw) {
        int u = ls[e], m = ld[e];
        float p = xu[(size_t)u * 64 + lane] * xm[(size_t)m * 64 + lane];
#pragma unroll
        for (int off = 32; off; off >>= 1) p += __shfl_down(p, off, 64);
        if (lane == 0) out[e] = p;
    }
}

// ---------------------------------------------------------------------------

extern "C" void kernel_launch(void* const* d_in, const int* in_sizes, int n_in,
                              void* d_out, int out_size, void* d_ws, size_t ws_size,
                              hipStream_t stream) {
    const float* movie_x   = (const float*)d_in[0];
    const float* user_emb  = (const float*)d_in[1];
    const float* movie_emb = (const float*)d_in[2];
    const float* mlw       = (const float*)d_in[3];
    const float* mlb       = (const float*)d_in[4];
    const float* llw       = (const float*)d_in[5];   // [2][2][64][64]
    const float* llb       = (const float*)d_in[6];   // [2][2][64]
    const float* lrw       = (const float*)d_in[7];   // [2][2][64][64]
    const int*   esrc      = (const int*)d_in[8];
    const int*   edst      = (const int*)d_in[9];
    const int*   lsrc      = (const int*)d_in[10];
    const int*   ldst      = (const int*)d_in[11];

    const int U = in_sizes[1] / 64;
    const int M = in_sizes[2] / 64;
    const int E = in_sizes[8];
    const int L = in_sizes[10];
    float* out = (float*)d_out;

    // ws layout
    float* A_m = (float*)d_ws;                      // [M,64] x_m layer0 in, reused as layer1 movie out
    float* B_m = A_m + (size_t)M * 64;              // [M,64] layer0 movie out
    float* B_u = B_m + (size_t)M * 64;              // [U,64] layer0 user out
    float* A_u = B_u + (size_t)U * 64;              // [U,64] layer1 user out
    int* rp_u  = (int*)(A_u + (size_t)U * 64);      // [U+1]
    int* rp_m  = rp_u + (U + 1);                    // [M+1]
    int* cnt_u = rp_m + (M + 1);                    // [U]   (contiguous with cnt_m)
    int* cnt_m = cnt_u + U;                         // [M]
    int* col_u = cnt_m + M;                         // [E]
    int* col_m = col_u + E;                         // [E]
    int* bs_u  = col_m + E;                         // [256]
    int* bs_m  = bs_u + 256;                        // [256]

    const int nb_u = (U + 1023) / 1024;
    const int nb_m = (M + 1023) / 1024;

    // ---- CSR build ----
    hipMemsetAsync(cnt_u, 0, (size_t)(U + M) * sizeof(int), stream);
    hist_kernel<<<(E + 255) / 256, 256, 0, stream>>>(esrc, edst, cnt_u, cnt_m, E);
    reduce_chunks<<<nb_u, 256, 0, stream>>>(cnt_u, U, bs_u);
    reduce_chunks<<<nb_m, 256, 0, stream>>>(cnt_m, M, bs_m);
    scan_bsums<<<1, 256, 0, stream>>>(bs_u, nb_u);
    scan_bsums<<<1, 256, 0, stream>>>(bs_m, nb_m);
    scan_chunks<<<nb_u, 256, 0, stream>>>(cnt_u, U, bs_u, rp_u, E);
    scan_chunks<<<nb_m, 256, 0, stream>>>(cnt_m, M, bs_m, rp_m, E);
    scatter_kernel<<<(E + 255) / 256, 256, 0, stream>>>(esrc, edst, rp_u, rp_m,
                                                        cnt_u, cnt_m, col_u, col_m, E);

    // ---- node init ----
    movie_init_kernel<<<1024, 256, 0, stream>>>(movie_x, mlw, mlb, movie_emb, A_m, M);

    const int gm = (M + 63) / 64, gu = (U + 63) / 64;
    // ---- layer 0 ----
    sage_fused<<<gm, 256, 0, stream>>>(rp_m, col_m, user_emb, A_m,
                                       llw + 0 * 4096, llb + 0 * 64, lrw + 0 * 4096,
                                       B_m, M, 1);
    sage_fused<<<gu, 256, 0, stream>>>(rp_u, col_u, A_m, user_emb,
                                       llw + 1 * 4096, llb + 1 * 64, lrw + 1 * 4096,
                                       B_u, U, 1);
    // ---- layer 1 ---- (A_m free now; reuse for movie output)
    sage_fused<<<gm, 256, 0, stream>>>(rp_m, col_m, B_u, B_m,
                                       llw + 2 * 4096, llb + 2 * 64, lrw + 2 * 4096,
                                       A_m, M, 0);
    sage_fused<<<gu, 256, 0, stream>>>(rp_u, col_u, B_m, B_u,
                                       llw + 3 * 4096, llb + 3 * 64, lrw + 3 * 4096,
                                       A_u, U, 0);

    // ---- link head ----
    dot_kernel<<<2048, 256, 0, stream>>>(lsrc, ldst, A_u, A_m, out, L);
}

// Round 3
// 995.344 us; speedup vs baseline: 2.4914x; 1.6865x over previous
//
#include <hip/hip_runtime.h>

// ---------------------------------------------------------------------------
// Round 3: de-fused pipeline.
//   CSR build (hist/scan/scatter) -> movie init -> weight transpose ->
//   per layer: gather_kernel (no LDS, wave/node, max occupancy) writes mean;
//              apply_kernel (two-phase LDS GEMM, conflict-free, in-place).
//   dot head unchanged.
// ---------------------------------------------------------------------------

// ---- CSR build ------------------------------------------------------------

__global__ void hist_kernel(const int* __restrict__ src, const int* __restrict__ dst,
                            int* __restrict__ cnt_u, int* __restrict__ cnt_m, int E) {
    int e = blockIdx.x * blockDim.x + threadIdx.x;
    if (e < E) {
        atomicAdd(&cnt_u[src[e]], 1);
        atomicAdd(&cnt_m[dst[e]], 1);
    }
}

__global__ void reduce_chunks(const int* __restrict__ cnt, int n, int* __restrict__ bsums) {
    __shared__ int red[256];
    int base = blockIdx.x * 1024;
    int s = 0;
    for (int k = 0; k < 4; ++k) {
        int i = base + k * 256 + threadIdx.x;
        if (i < n) s += cnt[i];
    }
    red[threadIdx.x] = s;
    __syncthreads();
    for (int off = 128; off; off >>= 1) {
        if (threadIdx.x < off) red[threadIdx.x] += red[threadIdx.x + off];
        __syncthreads();
    }
    if (threadIdx.x == 0) bsums[blockIdx.x] = red[0];
}

__global__ void scan_bsums(int* __restrict__ bsums, int nb) {
    __shared__ int s[256];
    int t = threadIdx.x;
    if (t < nb) s[t] = bsums[t];
    __syncthreads();
    if (t == 0) {
        int run = 0;
        for (int i = 0; i < nb; ++i) { int v = s[i]; s[i] = run; run += v; }
    }
    __syncthreads();
    if (t < nb) bsums[t] = s[t];
}

__global__ void scan_chunks(const int* __restrict__ cnt, int n,
                            const int* __restrict__ bsums,
                            int* __restrict__ row_ptr, int total) {
    __shared__ int sc[256];
    int t = threadIdx.x;
    int base = blockIdx.x * 1024 + t * 4;
    int4 v = make_int4(0, 0, 0, 0);
    if (base + 3 < n) v = *(const int4*)(cnt + base);
    else {
        if (base     < n) v.x = cnt[base];
        if (base + 1 < n) v.y = cnt[base + 1];
        if (base + 2 < n) v.z = cnt[base + 2];
    }
    int tsum = v.x + v.y + v.z + v.w;
    sc[t] = tsum;
    __syncthreads();
    for (int off = 1; off < 256; off <<= 1) {
        int val = sc[t];
        int add = (t >= off) ? sc[t - off] : 0;
        __syncthreads();
        sc[t] = val + add;
        __syncthreads();
    }
    int excl = sc[t] - tsum + bsums[blockIdx.x];
    int4 o;
    o.x = excl; o.y = o.x + v.x; o.z = o.y + v.y; o.w = o.z + v.z;
    if (base + 3 < n) *(int4*)(row_ptr + base) = o;
    else {
        if (base     < n) row_ptr[base]     = o.x;
        if (base + 1 < n) row_ptr[base + 1] = o.y;
        if (base + 2 < n) row_ptr[base + 2] = o.z;
    }
    if (blockIdx.x == 0 && t == 0) row_ptr[n] = total;
}

__global__ void scatter_kernel(const int* __restrict__ src, const int* __restrict__ dst,
                               const int* __restrict__ rp_u, const int* __restrict__ rp_m,
                               int* __restrict__ cnt_u, int* __restrict__ cnt_m,
                               int* __restrict__ col_u, int* __restrict__ col_m, int E) {
    int e = blockIdx.x * blockDim.x + threadIdx.x;
    if (e < E) {
        int s = src[e], d = dst[e];
        int pu = atomicSub(&cnt_u[s], 1) - 1;
        col_u[rp_u[s] + pu] = d;
        int pm = atomicSub(&cnt_m[d], 1) - 1;
        col_m[rp_m[d] + pm] = s;
    }
}

// ---- movie feature init ---------------------------------------------------

__global__ void movie_init_kernel(const float* __restrict__ movie_x,  // [M,20]
                                  const float* __restrict__ wm,       // [64,20]
                                  const float* __restrict__ bm,       // [64]
                                  const float* __restrict__ memb,     // [M,64]
                                  float* __restrict__ xm, int M) {
    __shared__ float w_s[64 * 21];
    int lane = threadIdx.x & 63;
    for (int i = threadIdx.x; i < 64 * 20; i += blockDim.x) {
        int h = i / 20, f = i % 20;
        w_s[h * 21 + f] = wm[i];
    }
    __syncthreads();
    float bias = bm[lane];
    int nw = (gridDim.x * blockDim.x) >> 6;
    int w  = (blockIdx.x * blockDim.x + threadIdx.x) >> 6;
    for (int m = w; m < M; m += nw) {
        float fv  = (lane < 20) ? movie_x[m * 20 + lane] : 0.0f;
        float acc = bias + memb[m * 64 + lane];
#pragma unroll
        for (int f = 0; f < 20; ++f) {
            float xv = __shfl(fv, f, 64);
            acc += xv * w_s[lane * 21 + f];
        }
        xm[m * 64 + lane] = acc;
    }
}

// ---- weight transpose: wT[set][k][h] = w[set][h][k], 4 sets of 64x64 ------

__global__ void wt_kernel(const float* __restrict__ llw, const float* __restrict__ lrw,
                          float* __restrict__ wTl, float* __restrict__ wTr) {
    int i = blockIdx.x * 256 + threadIdx.x;      // 0 .. 4*4096-1
    int s = i >> 12, rem = i & 4095, k = rem >> 6, h = rem & 63;
    wTl[i] = llw[s * 4096 + h * 64 + k];
    wTr[i] = lrw[s * 4096 + h * 64 + k];
}

// ---- gather: mean of neighbor rows, wave per node, max occupancy ----------

__global__ __launch_bounds__(256) void gather_kernel(
    const int* __restrict__ row_ptr, const int* __restrict__ col,
    const float* __restrict__ x_src, float* __restrict__ mean_out, int n) {
    int lane = threadIdx.x & 63;
    int node = (blockIdx.x * 256 + threadIdx.x) >> 6;
    if (node >= n) return;
    int beg = row_ptr[node], end = row_ptr[node + 1];
    float s0 = 0, s1 = 0, s2 = 0, s3 = 0, s4 = 0, s5 = 0, s6 = 0, s7 = 0;
    int j = beg;
    for (; j + 8 <= end; j += 8) {
        int c0 = col[j],     c1 = col[j + 1], c2 = col[j + 2], c3 = col[j + 3];
        int c4 = col[j + 4], c5 = col[j + 5], c6 = col[j + 6], c7 = col[j + 7];
        s0 += x_src[(size_t)c0 * 64 + lane];
        s1 += x_src[(size_t)c1 * 64 + lane];
        s2 += x_src[(size_t)c2 * 64 + lane];
        s3 += x_src[(size_t)c3 * 64 + lane];
        s4 += x_src[(size_t)c4 * 64 + lane];
        s5 += x_src[(size_t)c5 * 64 + lane];
        s6 += x_src[(size_t)c6 * 64 + lane];
        s7 += x_src[(size_t)c7 * 64 + lane];
    }
    for (; j < end; ++j) s0 += x_src[(size_t)col[j] * 64 + lane];
    float sum = ((s0 + s1) + (s2 + s3)) + ((s4 + s5) + (s6 + s7));
    mean_out[(size_t)node * 64 + lane] = sum / fmaxf((float)(end - beg), 1.0f);
}

// ---- apply: out = relu?( mean @ wlT + self @ wrT + b ), in-place on mean --
// Two phases share one LDS footprint (33 KB -> 4 blocks/CU). All LDS access
// conflict-free: coalesced staging, broadcast X reads, float4 broadcast W.

__global__ __launch_bounds__(256) void apply_kernel(
    float* __restrict__ xio,          // [n,64] mean in, output in-place
    const float* __restrict__ self_,  // [n,64]
    const float* __restrict__ wTl,    // [64][64] k-major
    const float* __restrict__ wTr,    // [64][64] k-major
    const float* __restrict__ bl,     // [64]
    int n, int do_relu) {
    __shared__ float Xs[64 * 66];
    __shared__ float Ws[64 * 64];
    int tid = threadIdx.x;
    int node0 = blockIdx.x * 64;
    int hg = tid & 7, ng = tid >> 3;          // 8 h-groups x 32 n-groups
    int h0 = hg * 8;
    int nA = ng * 2;

    float acc[2][8];
#pragma unroll
    for (int r = 0; r < 2; ++r)
#pragma unroll
        for (int c = 0; c < 8; ++c) acc[r][c] = 0.0f;

    for (int phase = 0; phase < 2; ++phase) {
        const float* X = phase ? self_ : xio;
        const float* W = phase ? wTr : wTl;
        __syncthreads();   // phase 1: protect previous phase's LDS reads
        for (int i = tid; i < 4096; i += 256) {
            int nn = i >> 6, kk = i & 63;
            int gi = node0 + nn;
            Xs[nn * 66 + kk] = (gi < n) ? X[(size_t)gi * 64 + kk] : 0.0f;
            Ws[i] = W[i];
        }
        __syncthreads();
#pragma unroll 8
        for (int k = 0; k < 64; ++k) {
            float xa = Xs[nA * 66 + k];
            float xb = Xs[(nA + 1) * 66 + k];
            float4 w0 = *(const float4*)&Ws[k * 64 + h0];
            float4 w1 = *(const float4*)&Ws[k * 64 + h0 + 4];
            float w[8] = {w0.x, w0.y, w0.z, w0.w, w1.x, w1.y, w1.z, w1.w};
#pragma unroll
            for (int c = 0; c < 8; ++c) {
                acc[0][c] += xa * w[c];
                acc[1][c] += xb * w[c];
            }
        }
    }

    float4 b0 = *(const float4*)&bl[h0];
    float4 b1 = *(const float4*)&bl[h0 + 4];
    float bias[8] = {b0.x, b0.y, b0.z, b0.w, b1.x, b1.y, b1.z, b1.w};
#pragma unroll
    for (int r = 0; r < 2; ++r) {
        int gi = node0 + nA + r;
        if (gi < n) {
            float o[8];
#pragma unroll
            for (int c = 0; c < 8; ++c) {
                float v = acc[r][c] + bias[c];
                o[c] = do_relu ? fmaxf(v, 0.0f) : v;
            }
            *(float4*)&xio[(size_t)gi * 64 + h0]     = make_float4(o[0], o[1], o[2], o[3]);
            *(float4*)&xio[(size_t)gi * 64 + h0 + 4] = make_float4(o[4], o[5], o[6], o[7]);
        }
    }
}

// ---- link head ------------------------------------------------------------

__global__ void dot_kernel(const int* __restrict__ ls, const int* __restrict__ ld,
                           const float* __restrict__ xu, const float* __restrict__ xm,
                           float* __restrict__ out, int L) {
    int lane = threadIdx.x & 63;
    int nw = (gridDim.x * blockDim.x) >> 6;
    int w  = (blockIdx.x * blockDim.x + threadIdx.x) >> 6;
    for (int e = w; e < L; e += nw) {
        int u = ls[e], m = ld[e];
        float p = xu[(size_t)u * 64 + lane] * xm[(size_t)m * 64 + lane];
#pragma unroll
        for (int off = 32; off; off >>= 1) p += __shfl_down(p, off, 64);
        if (lane == 0) out[e] = p;
    }
}

// ---------------------------------------------------------------------------

extern "C" void kernel_launch(void* const* d_in, const int* in_sizes, int n_in,
                              void* d_out, int out_size, void* d_ws, size_t ws_size,
                              hipStream_t stream) {
    const float* movie_x   = (const float*)d_in[0];
    const float* user_emb  = (const float*)d_in[1];
    const float* movie_emb = (const float*)d_in[2];
    const float* mlw       = (const float*)d_in[3];
    const float* mlb       = (const float*)d_in[4];
    const float* llw       = (const float*)d_in[5];   // [2][2][64][64]
    const float* llb       = (const float*)d_in[6];   // [2][2][64]
    const float* lrw       = (const float*)d_in[7];   // [2][2][64][64]
    const int*   esrc      = (const int*)d_in[8];
    const int*   edst      = (const int*)d_in[9];
    const int*   lsrc      = (const int*)d_in[10];
    const int*   ldst      = (const int*)d_in[11];

    const int U = in_sizes[1] / 64;
    const int M = in_sizes[2] / 64;
    const int E = in_sizes[8];
    const int L = in_sizes[10];
    float* out = (float*)d_out;

    const size_t M64 = (size_t)M * 64, U64 = (size_t)U * 64;

    // ws layout
    float* xm0 = (float*)d_ws;          // [M,64] init movie features
    float* xm1 = xm0 + M64;             // [M,64] L0 mean -> x_m layer0 (in-place)
    float* xm2 = xm1 + M64;             // [M,64] L1 mean -> x_m final
    float* xu1 = xm2 + M64;             // [U,64] L0 mean -> x_u layer0
    float* xu2 = xu1 + U64;             // [U,64] L1 mean -> x_u final
    float* wTl = xu2 + U64;             // [4][64][64]
    float* wTr = wTl + 4 * 4096;        // [4][64][64]
    int* rp_u  = (int*)(wTr + 4 * 4096);// [U+1]
    int* rp_m  = rp_u + (U + 1);        // [M+1]
    int* cnt_u = rp_m + (M + 1);        // [U] (contiguous with cnt_m)
    int* cnt_m = cnt_u + U;             // [M]
    int* col_u = cnt_m + M;             // [E]
    int* col_m = col_u + E;             // [E]
    int* bs_u  = col_m + E;             // [256]
    int* bs_m  = bs_u + 256;            // [256]

    const int nb_u = (U + 1023) / 1024;
    const int nb_m = (M + 1023) / 1024;

    // ---- CSR build ----
    hipMemsetAsync(cnt_u, 0, (size_t)(U + M) * sizeof(int), stream);
    hist_kernel<<<(E + 255) / 256, 256, 0, stream>>>(esrc, edst, cnt_u, cnt_m, E);
    reduce_chunks<<<nb_u, 256, 0, stream>>>(cnt_u, U, bs_u);
    reduce_chunks<<<nb_m, 256, 0, stream>>>(cnt_m, M, bs_m);
    scan_bsums<<<1, 256, 0, stream>>>(bs_u, nb_u);
    scan_bsums<<<1, 256, 0, stream>>>(bs_m, nb_m);
    scan_chunks<<<nb_u, 256, 0, stream>>>(cnt_u, U, bs_u, rp_u, E);
    scan_chunks<<<nb_m, 256, 0, stream>>>(cnt_m, M, bs_m, rp_m, E);
    scatter_kernel<<<(E + 255) / 256, 256, 0, stream>>>(esrc, edst, rp_u, rp_m,
                                                        cnt_u, cnt_m, col_u, col_m, E);

    // ---- node init + weight transpose ----
    movie_init_kernel<<<1024, 256, 0, stream>>>(movie_x, mlw, mlb, movie_emb, xm0, M);
    wt_kernel<<<64, 256, 0, stream>>>(llw, lrw, wTl, wTr);

    const int gm_g = (M * 64 + 255) / 256, gu_g = (U * 64 + 255) / 256;  // gather grids
    const int gm_a = (M + 63) / 64,        gu_a = (U + 63) / 64;         // apply grids

    // ---- layer 0 ----
    gather_kernel<<<gm_g, 256, 0, stream>>>(rp_m, col_m, user_emb, xm1, M);
    gather_kernel<<<gu_g, 256, 0, stream>>>(rp_u, col_u, xm0, xu1, U);
    apply_kernel<<<gm_a, 256, 0, stream>>>(xm1, xm0,
                                           wTl + 0 * 4096, wTr + 0 * 4096, llb + 0 * 64, M, 1);
    apply_kernel<<<gu_a, 256, 0, stream>>>(xu1, user_emb,
                                           wTl + 1 * 4096, wTr + 1 * 4096, llb + 1 * 64, U, 1);

    // ---- layer 1 ----
    gather_kernel<<<gm_g, 256, 0, stream>>>(rp_m, col_m, xu1, xm2, M);
    gather_kernel<<<gu_g, 256, 0, stream>>>(rp_u, col_u, xm1, xu2, U);
    apply_kernel<<<gm_a, 256, 0, stream>>>(xm2, xm1,
                                           wTl + 2 * 4096, wTr + 2 * 4096, llb + 2 * 64, M, 0);
    apply_kernel<<<gu_a, 256, 0, stream>>>(xu2, xu1,
                                           wTl + 3 * 4096, wTr + 3 * 4096, llb + 3 * 64, U, 0);

    // ---- link head ----
    dot_kernel<<<2048, 256, 0, stream>>>(lsrc, ldst, xu2, xm2, out, L);
}

// Round 4
// 752.596 us; speedup vs baseline: 3.2950x; 1.3225x over previous
//
#include <hip/hip_runtime.h>

// ---------------------------------------------------------------------------
// Round 4: LDS-binned two-level CSR build (no random global scatter).
//   coarse_hist (LDS bins, both dirs) -> scan_bucket -> per direction:
//   partition (8K-edge chunks, run-contiguous int2 writes) ->
//   fine_csr (block per 256-node bucket: LDS hist+scan -> rp, LDS-cursor
//   scatter -> col, all writes bucket-local).
//   Then: gather (wave/node, max occupancy) -> apply (LDS GEMM) x2 layers,
//   dot head. Part buffer aliases xu2.
// ---------------------------------------------------------------------------

#define CH 8192   // edges per partition block

// ---- coarse histogram: both directions in one pass ------------------------

__global__ __launch_bounds__(256) void coarse_hist(
    const int* __restrict__ src, const int* __restrict__ dst, int E,
    int* __restrict__ bcu, int* __restrict__ bcm, int nbu, int nbm) {
    __shared__ int hu[512];
    __shared__ int hm[512];
    int tid = threadIdx.x;
    for (int i = tid; i < 512; i += 256) { hu[i] = 0; hm[i] = 0; }
    __syncthreads();
    int stride = gridDim.x * 256;
    for (int e = blockIdx.x * 256 + tid; e < E; e += stride) {
        atomicAdd(&hu[src[e] >> 8], 1);
        atomicAdd(&hm[dst[e] >> 8], 1);
    }
    __syncthreads();
    for (int i = tid; i < nbu; i += 256) if (hu[i]) atomicAdd(&bcu[i], hu[i]);
    for (int i = tid; i < nbm; i += 256) if (hm[i]) atomicAdd(&bcm[i], hm[i]);
}

// ---- exclusive scan of bucket counts (single block, NB <= 512) ------------

__global__ void scan_bucket(const int* __restrict__ bcnt, int NB,
                            int* __restrict__ bptr, int* __restrict__ bfill, int E) {
    __shared__ int sc[512];
    int t = threadIdx.x;
    int v = (t < NB) ? bcnt[t] : 0;
    sc[t] = v;
    __syncthreads();
    for (int off = 1; off < 512; off <<= 1) {
        int val = sc[t];
        int add = (t >= off) ? sc[t - off] : 0;
        __syncthreads();
        sc[t] = val + add;
        __syncthreads();
    }
    int excl = sc[t] - v;
    if (t < NB) { bptr[t] = excl; bfill[t] = excl; }
    if (t == 0) bptr[NB] = E;
}

// ---- coarse partition: chunk -> LDS count -> reserve -> run writes --------

__global__ __launch_bounds__(256) void partition_kernel(
    const int* __restrict__ key, const int* __restrict__ val, int E, int NB,
    int* __restrict__ bfill, int2* __restrict__ part) {
    __shared__ int h[512];
    __shared__ int base[512];
    __shared__ int cur[512];
    int tid = threadIdx.x;
    int c0 = blockIdx.x * CH;
    int lim = min(c0 + CH, E);
    for (int i = tid; i < NB; i += 256) h[i] = 0;
    __syncthreads();
    for (int e = c0 + tid; e < lim; e += 256)
        atomicAdd(&h[key[e] >> 8], 1);
    __syncthreads();
    for (int i = tid; i < NB; i += 256) {
        int c = h[i];
        base[i] = c ? atomicAdd(&bfill[i], c) : 0;
        cur[i] = 0;
    }
    __syncthreads();
    for (int e = c0 + tid; e < lim; e += 256) {
        int k = key[e];
        int b = k >> 8;
        int off = atomicAdd(&cur[b], 1);
        part[(size_t)base[b] + off] = make_int2(k, val[e]);
    }
}

// ---- fine CSR: one block per bucket ---------------------------------------

__global__ __launch_bounds__(256) void fine_csr(
    const int2* __restrict__ part, const int* __restrict__ bptr,
    int* __restrict__ rp, int* __restrict__ col, int n, int E) {
    int b = blockIdx.x;
    int beg = bptr[b], end = bptr[b + 1];
    __shared__ int c[256];
    __shared__ int sc[256];
    int t = threadIdx.x;
    c[t] = 0;
    __syncthreads();
    for (int j = beg + t; j < end; j += 256)
        atomicAdd(&c[part[j].x & 255], 1);
    __syncthreads();
    int own = c[t];
    sc[t] = own;
    __syncthreads();
    for (int off = 1; off < 256; off <<= 1) {   // inclusive Hillis-Steele
        int val = sc[t];
        int add = (t >= off) ? sc[t - off] : 0;
        __syncthreads();
        sc[t] = val + add;
        __syncthreads();
    }
    int start = beg + sc[t] - own;              // global CSR offset for node
    int node = b * 256 + t;
    if (node < n) rp[node] = start;
    __syncthreads();
    c[t] = start;                               // reuse as cursor
    __syncthreads();
    for (int j = beg + t; j < end; j += 256) {
        int2 p = part[j];
        int off = atomicAdd(&c[p.x & 255], 1);
        col[off] = p.y;
    }
    if (b == 0 && t == 0) rp[n] = E;
}

// ---- movie feature init ---------------------------------------------------

__global__ void movie_init_kernel(const float* __restrict__ movie_x,  // [M,20]
                                  const float* __restrict__ wm,       // [64,20]
                                  const float* __restrict__ bm,       // [64]
                                  const float* __restrict__ memb,     // [M,64]
                                  float* __restrict__ xm, int M) {
    __shared__ float w_s[64 * 21];
    int lane = threadIdx.x & 63;
    for (int i = threadIdx.x; i < 64 * 20; i += blockDim.x) {
        int h = i / 20, f = i % 20;
        w_s[h * 21 + f] = wm[i];
    }
    __syncthreads();
    float bias = bm[lane];
    int nw = (gridDim.x * blockDim.x) >> 6;
    int w  = (blockIdx.x * blockDim.x + threadIdx.x) >> 6;
    for (int m = w; m < M; m += nw) {
        float fv  = (lane < 20) ? movie_x[m * 20 + lane] : 0.0f;
        float acc = bias + memb[m * 64 + lane];
#pragma unroll
        for (int f = 0; f < 20; ++f) {
            float xv = __shfl(fv, f, 64);
            acc += xv * w_s[lane * 21 + f];
        }
        xm[m * 64 + lane] = acc;
    }
}

// ---- weight transpose: wT[set][k][h] = w[set][h][k] -----------------------

__global__ void wt_kernel(const float* __restrict__ llw, const float* __restrict__ lrw,
                          float* __restrict__ wTl, float* __restrict__ wTr) {
    int i = blockIdx.x * 256 + threadIdx.x;      // 0 .. 4*4096-1
    int s = i >> 12, rem = i & 4095, k = rem >> 6, h = rem & 63;
    wTl[i] = llw[s * 4096 + h * 64 + k];
    wTr[i] = lrw[s * 4096 + h * 64 + k];
}

// ---- gather: mean of neighbor rows, wave per node -------------------------

__global__ __launch_bounds__(256) void gather_kernel(
    const int* __restrict__ row_ptr, const int* __restrict__ col,
    const float* __restrict__ x_src, float* __restrict__ mean_out, int n) {
    int lane = threadIdx.x & 63;
    int node = (blockIdx.x * 256 + threadIdx.x) >> 6;
    if (node >= n) return;
    int beg = row_ptr[node], end = row_ptr[node + 1];
    float s0 = 0, s1 = 0, s2 = 0, s3 = 0, s4 = 0, s5 = 0, s6 = 0, s7 = 0;
    int j = beg;
    for (; j + 8 <= end; j += 8) {
        int c0 = col[j],     c1 = col[j + 1], c2 = col[j + 2], c3 = col[j + 3];
        int c4 = col[j + 4], c5 = col[j + 5], c6 = col[j + 6], c7 = col[j + 7];
        s0 += x_src[(size_t)c0 * 64 + lane];
        s1 += x_src[(size_t)c1 * 64 + lane];
        s2 += x_src[(size_t)c2 * 64 + lane];
        s3 += x_src[(size_t)c3 * 64 + lane];
        s4 += x_src[(size_t)c4 * 64 + lane];
        s5 += x_src[(size_t)c5 * 64 + lane];
        s6 += x_src[(size_t)c6 * 64 + lane];
        s7 += x_src[(size_t)c7 * 64 + lane];
    }
    for (; j < end; ++j) s0 += x_src[(size_t)col[j] * 64 + lane];
    float sum = ((s0 + s1) + (s2 + s3)) + ((s4 + s5) + (s6 + s7));
    mean_out[(size_t)node * 64 + lane] = sum / fmaxf((float)(end - beg), 1.0f);
}

// ---- apply: out = relu?( mean @ wlT + self @ wrT + b ), in-place ----------

__global__ __launch_bounds__(256) void apply_kernel(
    float* __restrict__ xio,          // [n,64] mean in, output in-place
    const float* __restrict__ self_,  // [n,64]
    const float* __restrict__ wTl,    // [64][64] k-major
    const float* __restrict__ wTr,    // [64][64] k-major
    const float* __restrict__ bl,     // [64]
    int n, int do_relu) {
    __shared__ float Xs[64 * 66];
    __shared__ float Ws[64 * 64];
    int tid = threadIdx.x;
    int node0 = blockIdx.x * 64;
    int hg = tid & 7, ng = tid >> 3;
    int h0 = hg * 8;
    int nA = ng * 2;

    float acc[2][8];
#pragma unroll
    for (int r = 0; r < 2; ++r)
#pragma unroll
        for (int c = 0; c < 8; ++c) acc[r][c] = 0.0f;

    for (int phase = 0; phase < 2; ++phase) {
        const float* X = phase ? self_ : xio;
        const float* W = phase ? wTr : wTl;
        __syncthreads();
        for (int i = tid; i < 4096; i += 256) {
            int nn = i >> 6, kk = i & 63;
            int gi = node0 + nn;
            Xs[nn * 66 + kk] = (gi < n) ? X[(size_t)gi * 64 + kk] : 0.0f;
            Ws[i] = W[i];
        }
        __syncthreads();
#pragma unroll 8
        for (int k = 0; k < 64; ++k) {
            float xa = Xs[nA * 66 + k];
            float xb = Xs[(nA + 1) * 66 + k];
            float4 w0 = *(const float4*)&Ws[k * 64 + h0];
            float4 w1 = *(const float4*)&Ws[k * 64 + h0 + 4];
            float w[8] = {w0.x, w0.y, w0.z, w0.w, w1.x, w1.y, w1.z, w1.w};
#pragma unroll
            for (int c = 0; c < 8; ++c) {
                acc[0][c] += xa * w[c];
                acc[1][c] += xb * w[c];
            }
        }
    }

    float4 b0 = *(const float4*)&bl[h0];
    float4 b1 = *(const float4*)&bl[h0 + 4];
    float bias[8] = {b0.x, b0.y, b0.z, b0.w, b1.x, b1.y, b1.z, b1.w};
#pragma unroll
    for (int r = 0; r < 2; ++r) {
        int gi = node0 + nA + r;
        if (gi < n) {
            float o[8];
#pragma unroll
            for (int c = 0; c < 8; ++c) {
                float v = acc[r][c] + bias[c];
                o[c] = do_relu ? fmaxf(v, 0.0f) : v;
            }
            *(float4*)&xio[(size_t)gi * 64 + h0]     = make_float4(o[0], o[1], o[2], o[3]);
            *(float4*)&xio[(size_t)gi * 64 + h0 + 4] = make_float4(o[4], o[5], o[6], o[7]);
        }
    }
}

// ---- link head ------------------------------------------------------------

__global__ void dot_kernel(const int* __restrict__ ls, const int* __restrict__ ld,
                           const float* __restrict__ xu, const float* __restrict__ xm,
                           float* __restrict__ out, int L) {
    int lane = threadIdx.x & 63;
    int nw = (gridDim.x * blockDim.x) >> 6;
    int w  = (blockIdx.x * blockDim.x + threadIdx.x) >> 6;
    for (int e = w; e < L; e += nw) {
        int u = ls[e], m = ld[e];
        float p = xu[(size_t)u * 64 + lane] * xm[(size_t)m * 64 + lane];
#pragma unroll
        for (int off = 32; off; off >>= 1) p += __shfl_down(p, off, 64);
        if (lane == 0) out[e] = p;
    }
}

// ---------------------------------------------------------------------------

extern "C" void kernel_launch(void* const* d_in, const int* in_sizes, int n_in,
                              void* d_out, int out_size, void* d_ws, size_t ws_size,
                              hipStream_t stream) {
    const float* movie_x   = (const float*)d_in[0];
    const float* user_emb  = (const float*)d_in[1];
    const float* movie_emb = (const float*)d_in[2];
    const float* mlw       = (const float*)d_in[3];
    const float* mlb       = (const float*)d_in[4];
    const float* llw       = (const float*)d_in[5];   // [2][2][64][64]
    const float* llb       = (const float*)d_in[6];   // [2][2][64]
    const float* lrw       = (const float*)d_in[7];   // [2][2][64][64]
    const int*   esrc      = (const int*)d_in[8];
    const int*   edst      = (const int*)d_in[9];
    const int*   lsrc      = (const int*)d_in[10];
    const int*   ldst      = (const int*)d_in[11];

    const int U = in_sizes[1] / 64;
    const int M = in_sizes[2] / 64;
    const int E = in_sizes[8];
    const int L = in_sizes[10];
    float* out = (float*)d_out;

    const size_t M64 = (size_t)M * 64, U64 = (size_t)U * 64;
    const int nbu = (U + 255) >> 8;   // 391
    const int nbm = (M + 255) >> 8;   // 196

    // ws layout
    float* xm0 = (float*)d_ws;            // [M,64]
    float* xm1 = xm0 + M64;               // [M,64]
    float* xm2 = xm1 + M64;               // [M,64]
    float* xu1 = xm2 + M64;               // [U,64]
    float* xu2 = xu1 + U64;               // [U,64]  (aliased as part during CSR build)
    float* wTl = xu2 + U64;               // [4][64][64]
    float* wTr = wTl + 4 * 4096;          // [4][64][64]
    int* rp_u  = (int*)(wTr + 4 * 4096);  // [U+1]
    int* rp_m  = rp_u + (U + 1);          // [M+1]
    int* col_u = rp_m + (M + 1);          // [E]
    int* col_m = col_u + E;               // [E]
    int* bcu   = col_m + E;               // [512] coarse counts (contig w/ bcm)
    int* bcm   = bcu + 512;               // [512]
    int* bpu   = bcm + 512;               // [512+1]
    int* bpm   = bpu + 513;               // [512+1]
    int* bfu   = bpm + 513;               // [512]
    int* bfm   = bfu + 512;               // [512]
    int2* part = (int2*)xu2;              // [E] int2, 16 MB <= 25.6 MB

    // ---- CSR build ----
    hipMemsetAsync(bcu, 0, 1024 * sizeof(int), stream);
    coarse_hist<<<1024, 256, 0, stream>>>(esrc, edst, E, bcu, bcm, nbu, nbm);
    scan_bucket<<<1, 512, 0, stream>>>(bcu, nbu, bpu, bfu, E);
    scan_bucket<<<1, 512, 0, stream>>>(bcm, nbm, bpm, bfm, E);
    const int npart = (E + CH - 1) / CH;
    // direction m (key=dst, val=src) -> col_m, rp_m
    partition_kernel<<<npart, 256, 0, stream>>>(edst, esrc, E, nbm, bfm, part);
    fine_csr<<<nbm, 256, 0, stream>>>(part, bpm, rp_m, col_m, M, E);
    // direction u (key=src, val=dst) -> col_u, rp_u  (part buffer reused)
    partition_kernel<<<npart, 256, 0, stream>>>(esrc, edst, E, nbu, bfu, part);
    fine_csr<<<nbu, 256, 0, stream>>>(part, bpu, rp_u, col_u, U, E);

    // ---- node init + weight transpose ----
    movie_init_kernel<<<1024, 256, 0, stream>>>(movie_x, mlw, mlb, movie_emb, xm0, M);
    wt_kernel<<<64, 256, 0, stream>>>(llw, lrw, wTl, wTr);

    const int gm_g = (M * 64 + 255) / 256, gu_g = (U * 64 + 255) / 256;
    const int gm_a = (M + 63) / 64,        gu_a = (U + 63) / 64;

    // ---- layer 0 ----
    gather_kernel<<<gm_g, 256, 0, stream>>>(rp_m, col_m, user_emb, xm1, M);
    gather_kernel<<<gu_g, 256, 0, stream>>>(rp_u, col_u, xm0, xu1, U);
    apply_kernel<<<gm_a, 256, 0, stream>>>(xm1, xm0,
                                           wTl + 0 * 4096, wTr + 0 * 4096, llb + 0 * 64, M, 1);
    apply_kernel<<<gu_a, 256, 0, stream>>>(xu1, user_emb,
                                           wTl + 1 * 4096, wTr + 1 * 4096, llb + 1 * 64, U, 1);

    // ---- layer 1 ---- (xu2/part alias: CSR build finished long ago)
    gather_kernel<<<gm_g, 256, 0, stream>>>(rp_m, col_m, xu1, xm2, M);
    gather_kernel<<<gu_g, 256, 0, stream>>>(rp_u, col_u, xm1, xu2, U);
    apply_kernel<<<gm_a, 256, 0, stream>>>(xm2, xm1,
                                           wTl + 2 * 4096, wTr + 2 * 4096, llb + 2 * 64, M, 0);
    apply_kernel<<<gu_a, 256, 0, stream>>>(xu2, xu1,
                                           wTl + 3 * 4096, wTr + 3 * 4096, llb + 3 * 64, U, 0);

    // ---- link head ----
    dot_kernel<<<2048, 256, 0, stream>>>(lsrc, ldst, xu2, xm2, out, L);
}

// Round 5
// 622.149 us; speedup vs baseline: 3.9859x; 1.2097x over previous
//
#include <hip/hip_runtime.h>

// ---------------------------------------------------------------------------
// Round 5: bf16 gather-source tables (fp32 math elsewhere), single-pass
// dual-direction partition, 2-edge-per-wave dot head.
// Pipeline: coarse_hist -> scan_bucket x2 -> partition_both -> fine_csr x2 ->
// movie_init/wt -> cvt bf16 -> per layer: gather_bf16 x2, apply x2 -> dot.
// ws ~100 MB with aggressive aliasing (part_m=xu1, part_u=xu2, bu*=xu2, bm*
// single buffer reused across layers).
// ---------------------------------------------------------------------------

#define CH 8192   // edges per partition block

__device__ __forceinline__ float b2f(unsigned short u) {
    union { unsigned int i; float f; } v; v.i = ((unsigned int)u) << 16; return v.f;
}
__device__ __forceinline__ unsigned short f2b(float f) {
    union { float f; unsigned int i; } v; v.f = f;
    unsigned int i = v.i;
    return (unsigned short)((i + 0x7FFFu + ((i >> 16) & 1u)) >> 16);  // RNE
}

// ---- coarse histogram: both directions in one pass ------------------------

__global__ __launch_bounds__(256) void coarse_hist(
    const int* __restrict__ src, const int* __restrict__ dst, int E,
    int* __restrict__ bcu, int* __restrict__ bcm, int nbu, int nbm) {
    __shared__ int hu[512];
    __shared__ int hm[512];
    int tid = threadIdx.x;
    for (int i = tid; i < 512; i += 256) { hu[i] = 0; hm[i] = 0; }
    __syncthreads();
    int stride = gridDim.x * 256;
    for (int e = blockIdx.x * 256 + tid; e < E; e += stride) {
        atomicAdd(&hu[src[e] >> 8], 1);
        atomicAdd(&hm[dst[e] >> 8], 1);
    }
    __syncthreads();
    for (int i = tid; i < nbu; i += 256) if (hu[i]) atomicAdd(&bcu[i], hu[i]);
    for (int i = tid; i < nbm; i += 256) if (hm[i]) atomicAdd(&bcm[i], hm[i]);
}

// ---- exclusive scan of bucket counts (single block, NB <= 512) ------------

__global__ void scan_bucket(const int* __restrict__ bcnt, int NB,
                            int* __restrict__ bptr, int* __restrict__ bfill, int E) {
    __shared__ int sc[512];
    int t = threadIdx.x;
    int v = (t < NB) ? bcnt[t] : 0;
    sc[t] = v;
    __syncthreads();
    for (int off = 1; off < 512; off <<= 1) {
        int val = sc[t];
        int add = (t >= off) ? sc[t - off] : 0;
        __syncthreads();
        sc[t] = val + add;
        __syncthreads();
    }
    int excl = sc[t] - v;
    if (t < NB) { bptr[t] = excl; bfill[t] = excl; }
    if (t == 0) bptr[NB] = E;
}

// ---- partition both directions in one pass --------------------------------

__global__ __launch_bounds__(256) void partition_both(
    const int* __restrict__ src, const int* __restrict__ dst, int E,
    int nbu, int nbm, int* __restrict__ bfu, int* __restrict__ bfm,
    int2* __restrict__ pu, int2* __restrict__ pm) {
    __shared__ int hu[400], au[400], cu[400];
    __shared__ int hm[208], am[208], cm[208];
    int tid = threadIdx.x;
    int c0 = blockIdx.x * CH, lim = min(c0 + CH, E);
    for (int i = tid; i < 400; i += 256) hu[i] = 0;
    for (int i = tid; i < 208; i += 256) hm[i] = 0;
    __syncthreads();
    for (int e = c0 + tid; e < lim; e += 256) {
        atomicAdd(&hu[src[e] >> 8], 1);
        atomicAdd(&hm[dst[e] >> 8], 1);
    }
    __syncthreads();
    for (int i = tid; i < nbu; i += 256) {
        int c = hu[i];
        au[i] = c ? atomicAdd(&bfu[i], c) : 0;
        cu[i] = 0;
    }
    for (int i = tid; i < nbm; i += 256) {
        int c = hm[i];
        am[i] = c ? atomicAdd(&bfm[i], c) : 0;
        cm[i] = 0;
    }
    __syncthreads();
    for (int e = c0 + tid; e < lim; e += 256) {
        int s = src[e], d = dst[e];
        int bu_ = s >> 8, bm_ = d >> 8;
        int ou = atomicAdd(&cu[bu_], 1);
        pu[(size_t)au[bu_] + ou] = make_int2(s, d);
        int om = atomicAdd(&cm[bm_], 1);
        pm[(size_t)am[bm_] + om] = make_int2(d, s);
    }
}

// ---- fine CSR: one block per 256-node bucket ------------------------------

__global__ __launch_bounds__(256) void fine_csr(
    const int2* __restrict__ part, const int* __restrict__ bptr,
    int* __restrict__ rp, int* __restrict__ col, int n, int E) {
    int b = blockIdx.x;
    int beg = bptr[b], end = bptr[b + 1];
    __shared__ int c[256];
    __shared__ int sc[256];
    int t = threadIdx.x;
    c[t] = 0;
    __syncthreads();
    for (int j = beg + t; j < end; j += 256)
        atomicAdd(&c[part[j].x & 255], 1);
    __syncthreads();
    int own = c[t];
    sc[t] = own;
    __syncthreads();
    for (int off = 1; off < 256; off <<= 1) {
        int val = sc[t];
        int add = (t >= off) ? sc[t - off] : 0;
        __syncthreads();
        sc[t] = val + add;
        __syncthreads();
    }
    int start = beg + sc[t] - own;
    int node = b * 256 + t;
    if (node < n) rp[node] = start;
    __syncthreads();
    c[t] = start;
    __syncthreads();
    for (int j = beg + t; j < end; j += 256) {
        int2 p = part[j];
        int off = atomicAdd(&c[p.x & 255], 1);
        col[off] = p.y;
    }
    if (b == 0 && t == 0) rp[n] = E;
}

// ---- movie feature init ---------------------------------------------------

__global__ void movie_init_kernel(const float* __restrict__ movie_x,  // [M,20]
                                  const float* __restrict__ wm,       // [64,20]
                                  const float* __restrict__ bm,       // [64]
                                  const float* __restrict__ memb,     // [M,64]
                                  float* __restrict__ xm, int M) {
    __shared__ float w_s[64 * 21];
    int lane = threadIdx.x & 63;
    for (int i = threadIdx.x; i < 64 * 20; i += blockDim.x) {
        int h = i / 20, f = i % 20;
        w_s[h * 21 + f] = wm[i];
    }
    __syncthreads();
    float bias = bm[lane];
    int nw = (gridDim.x * blockDim.x) >> 6;
    int w  = (blockIdx.x * blockDim.x + threadIdx.x) >> 6;
    for (int m = w; m < M; m += nw) {
        float fv  = (lane < 20) ? movie_x[m * 20 + lane] : 0.0f;
        float acc = bias + memb[m * 64 + lane];
#pragma unroll
        for (int f = 0; f < 20; ++f) {
            float xv = __shfl(fv, f, 64);
            acc += xv * w_s[lane * 21 + f];
        }
        xm[m * 64 + lane] = acc;
    }
}

// ---- weight transpose: wT[set][k][h] = w[set][h][k] -----------------------

__global__ void wt_kernel(const float* __restrict__ llw, const float* __restrict__ lrw,
                          float* __restrict__ wTl, float* __restrict__ wTr) {
    int i = blockIdx.x * 256 + threadIdx.x;      // 0 .. 4*4096-1
    int s = i >> 12, rem = i & 4095, k = rem >> 6, h = rem & 63;
    wTl[i] = llw[s * 4096 + h * 64 + k];
    wTr[i] = lrw[s * 4096 + h * 64 + k];
}

// ---- fp32 -> bf16 table convert ------------------------------------------

__global__ void cvt_bf16(const float* __restrict__ x, unsigned short* __restrict__ y, int n4) {
    int i = blockIdx.x * 256 + threadIdx.x;
    if (i < n4) {
        float4 v = ((const float4*)x)[i];
        ushort4 o;
        o.x = f2b(v.x); o.y = f2b(v.y); o.z = f2b(v.z); o.w = f2b(v.w);
        ((ushort4*)y)[i] = o;
    }
}

// ---- gather: mean of bf16 neighbor rows, wave per node, 4 rows/instr ------
// lane = (group g in 0..3) x (quarter q in 0..15); group g handles neighbors
// beg+g, beg+g+4, ...; each lane reads ushort4 (dims 4q..4q+3, 8 B) so one
// wave instruction touches 4 rows x 128 B. fp32 accumulate, shfl_xor reduce.

__global__ __launch_bounds__(256) void gather_bf16(
    const int* __restrict__ rp, const int* __restrict__ col,
    const unsigned short* __restrict__ xb, float* __restrict__ mean_out, int n) {
    int node = (blockIdx.x * 256 + threadIdx.x) >> 6;
    if (node >= n) return;
    int lane = threadIdx.x & 63;
    int g = lane >> 4, q = lane & 15;
    int beg = rp[node], end = rp[node + 1];
    float a0 = 0, a1 = 0, a2 = 0, a3 = 0;
    float b0 = 0, b1 = 0, b2 = 0, b3 = 0;
    int j = beg + g;
    for (; j + 4 < end; j += 8) {
        int n0 = col[j], n1 = col[j + 4];
        ushort4 u0 = *(const ushort4*)(xb + (size_t)n0 * 64 + q * 4);
        ushort4 u1 = *(const ushort4*)(xb + (size_t)n1 * 64 + q * 4);
        a0 += b2f(u0.x); a1 += b2f(u0.y); a2 += b2f(u0.z); a3 += b2f(u0.w);
        b0 += b2f(u1.x); b1 += b2f(u1.y); b2 += b2f(u1.z); b3 += b2f(u1.w);
    }
    if (j < end) {
        int n0 = col[j];
        ushort4 u0 = *(const ushort4*)(xb + (size_t)n0 * 64 + q * 4);
        a0 += b2f(u0.x); a1 += b2f(u0.y); a2 += b2f(u0.z); a3 += b2f(u0.w);
    }
    a0 += b0; a1 += b1; a2 += b2; a3 += b3;
    a0 += __shfl_xor(a0, 16, 64); a0 += __shfl_xor(a0, 32, 64);
    a1 += __shfl_xor(a1, 16, 64); a1 += __shfl_xor(a1, 32, 64);
    a2 += __shfl_xor(a2, 16, 64); a2 += __shfl_xor(a2, 32, 64);
    a3 += __shfl_xor(a3, 16, 64); a3 += __shfl_xor(a3, 32, 64);
    if (g == 0) {
        float inv = 1.0f / fmaxf((float)(end - beg), 1.0f);
        *(float4*)&mean_out[(size_t)node * 64 + q * 4] =
            make_float4(a0 * inv, a1 * inv, a2 * inv, a3 * inv);
    }
}

// ---- apply: out = relu?( mean @ wlT + self @ wrT + b ), in-place ----------
// Optional bf16 mirror write for next layer's gather source.

__global__ __launch_bounds__(256) void apply_kernel(
    float* __restrict__ xio,          // [n,64] mean in, output in-place
    const float* __restrict__ self_,  // [n,64]
    const float* __restrict__ wTl,    // [64][64] k-major
    const float* __restrict__ wTr,    // [64][64] k-major
    const float* __restrict__ bl,     // [64]
    unsigned short* __restrict__ bf_out,  // [n,64] bf16 mirror or null
    int n, int do_relu) {
    __shared__ float Xs[64 * 66];
    __shared__ float Ws[64 * 64];
    int tid = threadIdx.x;
    int node0 = blockIdx.x * 64;
    int hg = tid & 7, ng = tid >> 3;
    int h0 = hg * 8;
    int nA = ng * 2;

    float acc[2][8];
#pragma unroll
    for (int r = 0; r < 2; ++r)
#pragma unroll
        for (int c = 0; c < 8; ++c) acc[r][c] = 0.0f;

    for (int phase = 0; phase < 2; ++phase) {
        const float* X = phase ? self_ : xio;
        const float* W = phase ? wTr : wTl;
        __syncthreads();
        for (int i = tid; i < 4096; i += 256) {
            int nn = i >> 6, kk = i & 63;
            int gi = node0 + nn;
            Xs[nn * 66 + kk] = (gi < n) ? X[(size_t)gi * 64 + kk] : 0.0f;
            Ws[i] = W[i];
        }
        __syncthreads();
#pragma unroll 8
        for (int k = 0; k < 64; ++k) {
            float xa = Xs[nA * 66 + k];
            float xb = Xs[(nA + 1) * 66 + k];
            float4 w0 = *(const float4*)&Ws[k * 64 + h0];
            float4 w1 = *(const float4*)&Ws[k * 64 + h0 + 4];
            float w[8] = {w0.x, w0.y, w0.z, w0.w, w1.x, w1.y, w1.z, w1.w};
#pragma unroll
            for (int c = 0; c < 8; ++c) {
                acc[0][c] += xa * w[c];
                acc[1][c] += xb * w[c];
            }
        }
    }

    float4 b0 = *(const float4*)&bl[h0];
    float4 b1 = *(const float4*)&bl[h0 + 4];
    float bias[8] = {b0.x, b0.y, b0.z, b0.w, b1.x, b1.y, b1.z, b1.w};
#pragma unroll
    for (int r = 0; r < 2; ++r) {
        int gi = node0 + nA + r;
        if (gi < n) {
            float o[8];
#pragma unroll
            for (int c = 0; c < 8; ++c) {
                float v = acc[r][c] + bias[c];
                o[c] = do_relu ? fmaxf(v, 0.0f) : v;
            }
            *(float4*)&xio[(size_t)gi * 64 + h0]     = make_float4(o[0], o[1], o[2], o[3]);
            *(float4*)&xio[(size_t)gi * 64 + h0 + 4] = make_float4(o[4], o[5], o[6], o[7]);
            if (bf_out) {
                ushort4 p0, p1;
                p0.x = f2b(o[0]); p0.y = f2b(o[1]); p0.z = f2b(o[2]); p0.w = f2b(o[3]);
                p1.x = f2b(o[4]); p1.y = f2b(o[5]); p1.z = f2b(o[6]); p1.w = f2b(o[7]);
                *(ushort4*)&bf_out[(size_t)gi * 64 + h0]     = p0;
                *(ushort4*)&bf_out[(size_t)gi * 64 + h0 + 4] = p1;
            }
        }
    }
}

// ---- link head: 2 edges per wave, float2 lanes ----------------------------

__global__ __launch_bounds__(256) void dot_kernel(
    const int* __restrict__ ls, const int* __restrict__ ld,
    const float* __restrict__ xu, const float* __restrict__ xm,
    float* __restrict__ out, int L) {
    int t = blockIdx.x * 256 + threadIdx.x;
    int lane = threadIdx.x & 63;
    int half = lane >> 5, q = lane & 31;
    int e = (t >> 6) * 2 + half;
    if (e < L) {
        int u = ls[e], m = ld[e];
        float2 a = *(const float2*)&xu[(size_t)u * 64 + q * 2];
        float2 b = *(const float2*)&xm[(size_t)m * 64 + q * 2];
        float p = a.x * b.x + a.y * b.y;
#pragma unroll
        for (int off = 1; off < 32; off <<= 1) p += __shfl_xor(p, off, 64);
        if (q == 0) out[e] = p;
    }
}

// ---------------------------------------------------------------------------

extern "C" void kernel_launch(void* const* d_in, const int* in_sizes, int n_in,
                              void* d_out, int out_size, void* d_ws, size_t ws_size,
                              hipStream_t stream) {
    const float* movie_x   = (const float*)d_in[0];
    const float* user_emb  = (const float*)d_in[1];
    const float* movie_emb = (const float*)d_in[2];
    const float* mlw       = (const float*)d_in[3];
    const float* mlb       = (const float*)d_in[4];
    const float* llw       = (const float*)d_in[5];   // [2][2][64][64]
    const float* llb       = (const float*)d_in[6];   // [2][2][64]
    const float* lrw       = (const float*)d_in[7];   // [2][2][64][64]
    const int*   esrc      = (const int*)d_in[8];
    const int*   edst      = (const int*)d_in[9];
    const int*   lsrc      = (const int*)d_in[10];
    const int*   ldst      = (const int*)d_in[11];

    const int U = in_sizes[1] / 64;
    const int M = in_sizes[2] / 64;
    const int E = in_sizes[8];
    const int L = in_sizes[10];
    float* out = (float*)d_out;

    const size_t M64 = (size_t)M * 64, U64 = (size_t)U * 64;
    const int nbu = (U + 255) >> 8;
    const int nbm = (M + 255) >> 8;

    // ws layout (~100 MB):
    float* xm0 = (float*)d_ws;            // [M,64] init movie feat; L1 movie mean/out
    float* xm1 = xm0 + M64;               // [M,64] L0 movie mean/out
    float* xu1 = xm1 + M64;               // [U,64] L0 user mean/out (part_m alias)
    float* xu2 = xu1 + U64;               // [U,64] L1 user mean/out (part_u, buB alias)
    float* wTl = xu2 + U64;               // [4][64][64]
    float* wTr = wTl + 4 * 4096;          // [4][64][64]
    unsigned short* bmB = (unsigned short*)(wTr + 4 * 4096);  // [M,64] bf16 (bm0/bm1)
    int* rp_u  = (int*)(bmB + M64);       // [U+1]
    int* rp_m  = rp_u + (U + 1);          // [M+1]
    int* col_u = rp_m + (M + 1);          // [E]
    int* col_m = col_u + E;               // [E]
    int* bcu   = col_m + E;               // [512]
    int* bcm   = bcu + 512;               // [512]
    int* bpu   = bcm + 512;               // [513]
    int* bpm   = bpu + 513;               // [513]
    int* bfu   = bpm + 513;               // [512]
    int* bfm   = bfu + 512;               // [512]
    int2* part_m = (int2*)xu1;            // [E] int2 (16 MB <= 25.6 MB)
    int2* part_u = (int2*)xu2;            // [E] int2
    unsigned short* buB = (unsigned short*)xu2;  // [U,64] bf16 (bu0/bu1), after part_u dead

    // ---- CSR build ----
    hipMemsetAsync(bcu, 0, 1024 * sizeof(int), stream);
    coarse_hist<<<1024, 256, 0, stream>>>(esrc, edst, E, bcu, bcm, nbu, nbm);
    scan_bucket<<<1, 512, 0, stream>>>(bcu, nbu, bpu, bfu, E);
    scan_bucket<<<1, 512, 0, stream>>>(bcm, nbm, bpm, bfm, E);
    const int npart = (E + CH - 1) / CH;
    partition_both<<<npart, 256, 0, stream>>>(esrc, edst, E, nbu, nbm, bfu, bfm,
                                              part_u, part_m);
    fine_csr<<<nbm, 256, 0, stream>>>(part_m, bpm, rp_m, col_m, M, E);
    fine_csr<<<nbu, 256, 0, stream>>>(part_u, bpu, rp_u, col_u, U, E);

    // ---- node init + weight transpose + bf16 sources ----
    movie_init_kernel<<<1024, 256, 0, stream>>>(movie_x, mlw, mlb, movie_emb, xm0, M);
    wt_kernel<<<64, 256, 0, stream>>>(llw, lrw, wTl, wTr);
    cvt_bf16<<<(U * 16 + 255) / 256, 256, 0, stream>>>(user_emb, buB, U * 16);  // bu0
    cvt_bf16<<<(M * 16 + 255) / 256, 256, 0, stream>>>(xm0, bmB, M * 16);       // bm0

    const int gm_g = (M * 64 + 255) / 256, gu_g = (U * 64 + 255) / 256;
    const int gm_a = (M + 63) / 64,        gu_a = (U + 63) / 64;

    // ---- layer 0 ----
    gather_bf16<<<gm_g, 256, 0, stream>>>(rp_m, col_m, buB, xm1, M);   // uses bu0
    gather_bf16<<<gu_g, 256, 0, stream>>>(rp_u, col_u, bmB, xu1, U);   // uses bm0
    apply_kernel<<<gm_a, 256, 0, stream>>>(xm1, xm0,
                                           wTl + 0 * 4096, wTr + 0 * 4096, llb + 0 * 64,
                                           bmB, M, 1);                  // writes bm1
    apply_kernel<<<gu_a, 256, 0, stream>>>(xu1, user_emb,
                                           wTl + 1 * 4096, wTr + 1 * 4096, llb + 1 * 64,
                                           buB, U, 1);                  // writes bu1

    // ---- layer 1 ----
    gather_bf16<<<gm_g, 256, 0, stream>>>(rp_m, col_m, buB, xm0, M);   // bu1 -> movie mean
    gather_bf16<<<gu_g, 256, 0, stream>>>(rp_u, col_u, bmB, xu2, U);   // bm1 -> user mean (clobbers buB: already consumed)
    apply_kernel<<<gm_a, 256, 0, stream>>>(xm0, xm1,
                                           wTl + 2 * 4096, wTr + 2 * 4096, llb + 2 * 64,
                                           (unsigned short*)nullptr, M, 0);
    apply_kernel<<<gu_a, 256, 0, stream>>>(xu2, xu1,
                                           wTl + 3 * 4096, wTr + 3 * 4096, llb + 3 * 64,
                                           (unsigned short*)nullptr, U, 0);

    // ---- link head ----
    dot_kernel<<<(((L + 1) / 2) * 64 + 255) / 256, 256, 0, stream>>>(lsrc, ldst, xu2, xm0, out, L);
}

// Round 6
// 557.878 us; speedup vs baseline: 4.4450x; 1.1152x over previous
//
#include <hip/hip_runtime.h>

// ---------------------------------------------------------------------------
// Round 6: bf16 dot head (final applies write bf16 mirrors), fused kernel
// pairs (gather/apply/fine_csr/scan duals -> 13 launches), balanced 128-node
// movie buckets / 256-node user buckets for the CSR build.
// ---------------------------------------------------------------------------

#define CH 8192   // edges per partition block

__device__ __forceinline__ float b2f(unsigned short u) {
    union { unsigned int i; float f; } v; v.i = ((unsigned int)u) << 16; return v.f;
}
__device__ __forceinline__ unsigned short f2b(float f) {
    union { float f; unsigned int i; } v; v.f = f;
    unsigned int i = v.i;
    return (unsigned short)((i + 0x7FFFu + ((i >> 16) & 1u)) >> 16);  // RNE
}

// ---- coarse histogram: u buckets = src>>8, m buckets = dst>>7 -------------

__global__ __launch_bounds__(256) void coarse_hist(
    const int* __restrict__ src, const int* __restrict__ dst, int E,
    int* __restrict__ bcu, int* __restrict__ bcm, int nbu, int nbm) {
    __shared__ int hu[400];
    __shared__ int hm[400];
    int tid = threadIdx.x;
    for (int i = tid; i < 400; i += 256) { hu[i] = 0; hm[i] = 0; }
    __syncthreads();
    int stride = gridDim.x * 256;
    for (int e = blockIdx.x * 256 + tid; e < E; e += stride) {
        atomicAdd(&hu[src[e] >> 8], 1);
        atomicAdd(&hm[dst[e] >> 7], 1);
    }
    __syncthreads();
    for (int i = tid; i < nbu; i += 256) if (hu[i]) atomicAdd(&bcu[i], hu[i]);
    for (int i = tid; i < nbm; i += 256) if (hm[i]) atomicAdd(&bcm[i], hm[i]);
}

// ---- dual exclusive scan: block 0 = u, block 1 = m (NB <= 512) ------------

__global__ void scan_dual(const int* __restrict__ bcu, int nbu,
                          int* __restrict__ bpu, int* __restrict__ bfu,
                          const int* __restrict__ bcm, int nbm,
                          int* __restrict__ bpm, int* __restrict__ bfm, int E) {
    const int* bcnt; int NB; int* bptr; int* bfill;
    if (blockIdx.x == 0) { bcnt = bcu; NB = nbu; bptr = bpu; bfill = bfu; }
    else                 { bcnt = bcm; NB = nbm; bptr = bpm; bfill = bfm; }
    __shared__ int sc[512];
    int t = threadIdx.x;
    int v = (t < NB) ? bcnt[t] : 0;
    sc[t] = v;
    __syncthreads();
    for (int off = 1; off < 512; off <<= 1) {
        int val = sc[t];
        int add = (t >= off) ? sc[t - off] : 0;
        __syncthreads();
        sc[t] = val + add;
        __syncthreads();
    }
    int excl = sc[t] - v;
    if (t < NB) { bptr[t] = excl; bfill[t] = excl; }
    if (t == 0) bptr[NB] = E;
}

// ---- partition both directions in one pass --------------------------------

__global__ __launch_bounds__(256) void partition_both(
    const int* __restrict__ src, const int* __restrict__ dst, int E,
    int nbu, int nbm, int* __restrict__ bfu, int* __restrict__ bfm,
    int2* __restrict__ pu, int2* __restrict__ pm) {
    __shared__ int hu[400], au[400], cu[400];
    __shared__ int hm[400], am[400], cm[400];
    int tid = threadIdx.x;
    int c0 = blockIdx.x * CH, lim = min(c0 + CH, E);
    for (int i = tid; i < 400; i += 256) { hu[i] = 0; hm[i] = 0; }
    __syncthreads();
    for (int e = c0 + tid; e < lim; e += 256) {
        atomicAdd(&hu[src[e] >> 8], 1);
        atomicAdd(&hm[dst[e] >> 7], 1);
    }
    __syncthreads();
    for (int i = tid; i < nbu; i += 256) {
        int c = hu[i];
        au[i] = c ? atomicAdd(&bfu[i], c) : 0;
        cu[i] = 0;
    }
    for (int i = tid; i < nbm; i += 256) {
        int c = hm[i];
        am[i] = c ? atomicAdd(&bfm[i], c) : 0;
        cm[i] = 0;
    }
    __syncthreads();
    for (int e = c0 + tid; e < lim; e += 256) {
        int s = src[e], d = dst[e];
        int bu_ = s >> 8, bm_ = d >> 7;
        int ou = atomicAdd(&cu[bu_], 1);
        pu[(size_t)au[bu_] + ou] = make_int2(s, d);
        int om = atomicAdd(&cm[bm_], 1);
        pm[(size_t)am[bm_] + om] = make_int2(d, s);
    }
}

// ---- fine CSR, both directions: m buckets = 128 nodes, u = 256 ------------

__global__ __launch_bounds__(256) void fine_dual(
    int nbm, const int2* __restrict__ pm, const int* __restrict__ bpm,
    int* __restrict__ rp_m, int* __restrict__ col_m, int M,
    const int2* __restrict__ pu, const int* __restrict__ bpu,
    int* __restrict__ rp_u, int* __restrict__ col_u, int U, int E) {
    int b = blockIdx.x;
    const int2* part; const int* bptr; int* rp; int* col; int n, npb;
    if (b < nbm) { part = pm; bptr = bpm; rp = rp_m; col = col_m; n = M; npb = 128; }
    else { b -= nbm; part = pu; bptr = bpu; rp = rp_u; col = col_u; n = U; npb = 256; }
    int beg = bptr[b], end = bptr[b + 1];
    __shared__ int c[256];
    __shared__ int sc[256];
    int t = threadIdx.x;
    c[t] = 0;
    __syncthreads();
    int mask = npb - 1;
    for (int j = beg + t; j < end; j += 256)
        atomicAdd(&c[part[j].x & mask], 1);
    __syncthreads();
    int own = c[t];
    sc[t] = own;
    __syncthreads();
    for (int off = 1; off < 256; off <<= 1) {
        int val = sc[t];
        int add = (t >= off) ? sc[t - off] : 0;
        __syncthreads();
        sc[t] = val + add;
        __syncthreads();
    }
    int start = beg + sc[t] - own;
    int node = b * npb + t;
    if (t < npb && node < n) rp[node] = start;
    __syncthreads();
    c[t] = start;
    __syncthreads();
    for (int j = beg + t; j < end; j += 256) {
        int2 p = part[j];
        int off = atomicAdd(&c[p.x & mask], 1);
        col[off] = p.y;
    }
    if (b == 0 && t == 0) rp[n] = E;
}

// ---- movie feature init (fp32 + bf16 mirror) ------------------------------

__global__ void movie_init_kernel(const float* __restrict__ movie_x,  // [M,20]
                                  const float* __restrict__ wm,       // [64,20]
                                  const float* __restrict__ bm,       // [64]
                                  const float* __restrict__ memb,     // [M,64]
                                  float* __restrict__ xm,
                                  unsigned short* __restrict__ xmB, int M) {
    __shared__ float w_s[64 * 21];
    int lane = threadIdx.x & 63;
    for (int i = threadIdx.x; i < 64 * 20; i += blockDim.x) {
        int h = i / 20, f = i % 20;
        w_s[h * 21 + f] = wm[i];
    }
    __syncthreads();
    float bias = bm[lane];
    int nw = (gridDim.x * blockDim.x) >> 6;
    int w  = (blockIdx.x * blockDim.x + threadIdx.x) >> 6;
    for (int m = w; m < M; m += nw) {
        float fv  = (lane < 20) ? movie_x[m * 20 + lane] : 0.0f;
        float acc = bias + memb[m * 64 + lane];
#pragma unroll
        for (int f = 0; f < 20; ++f) {
            float xv = __shfl(fv, f, 64);
            acc += xv * w_s[lane * 21 + f];
        }
        xm[m * 64 + lane] = acc;
        xmB[m * 64 + lane] = f2b(acc);
    }
}

// ---- weight transpose: wT[set][k][h] = w[set][h][k] -----------------------

__global__ void wt_kernel(const float* __restrict__ llw, const float* __restrict__ lrw,
                          float* __restrict__ wTl, float* __restrict__ wTr) {
    int i = blockIdx.x * 256 + threadIdx.x;      // 0 .. 4*4096-1
    int s = i >> 12, rem = i & 4095, k = rem >> 6, h = rem & 63;
    wTl[i] = llw[s * 4096 + h * 64 + k];
    wTr[i] = lrw[s * 4096 + h * 64 + k];
}

// ---- fp32 -> bf16 table convert ------------------------------------------

__global__ void cvt_bf16(const float* __restrict__ x, unsigned short* __restrict__ y, int n4) {
    int i = blockIdx.x * 256 + threadIdx.x;
    if (i < n4) {
        float4 v = ((const float4*)x)[i];
        ushort4 o;
        o.x = f2b(v.x); o.y = f2b(v.y); o.z = f2b(v.z); o.w = f2b(v.w);
        ((ushort4*)y)[i] = o;
    }
}

// ---- dual gather: mean of bf16 neighbor rows, wave per node ---------------

__global__ __launch_bounds__(256) void gather_dual(
    int gm,
    const int* __restrict__ rp_m, const int* __restrict__ col_m,
    const unsigned short* __restrict__ srcU, float* __restrict__ outM, int M,
    const int* __restrict__ rp_u, const int* __restrict__ col_u,
    const unsigned short* __restrict__ srcM, float* __restrict__ outU, int U) {
    int b = blockIdx.x;
    const int* rp; const int* col; const unsigned short* xb; float* mo; int n;
    if (b < gm) { rp = rp_m; col = col_m; xb = srcU; mo = outM; n = M; }
    else { b -= gm; rp = rp_u; col = col_u; xb = srcM; mo = outU; n = U; }
    int node = (b * 256 + threadIdx.x) >> 6;
    if (node >= n) return;
    int lane = threadIdx.x & 63;
    int g = lane >> 4, q = lane & 15;
    int beg = rp[node], end = rp[node + 1];
    float a0 = 0, a1 = 0, a2 = 0, a3 = 0;
    float b0 = 0, b1 = 0, b2 = 0, b3 = 0;
    int j = beg + g;
    for (; j + 4 < end; j += 8) {
        int n0 = col[j], n1 = col[j + 4];
        ushort4 u0 = *(const ushort4*)(xb + (size_t)n0 * 64 + q * 4);
        ushort4 u1 = *(const ushort4*)(xb + (size_t)n1 * 64 + q * 4);
        a0 += b2f(u0.x); a1 += b2f(u0.y); a2 += b2f(u0.z); a3 += b2f(u0.w);
        b0 += b2f(u1.x); b1 += b2f(u1.y); b2 += b2f(u1.z); b3 += b2f(u1.w);
    }
    if (j < end) {
        int n0 = col[j];
        ushort4 u0 = *(const ushort4*)(xb + (size_t)n0 * 64 + q * 4);
        a0 += b2f(u0.x); a1 += b2f(u0.y); a2 += b2f(u0.z); a3 += b2f(u0.w);
    }
    a0 += b0; a1 += b1; a2 += b2; a3 += b3;
    a0 += __shfl_xor(a0, 16, 64); a0 += __shfl_xor(a0, 32, 64);
    a1 += __shfl_xor(a1, 16, 64); a1 += __shfl_xor(a1, 32, 64);
    a2 += __shfl_xor(a2, 16, 64); a2 += __shfl_xor(a2, 32, 64);
    a3 += __shfl_xor(a3, 16, 64); a3 += __shfl_xor(a3, 32, 64);
    if (g == 0) {
        float inv = 1.0f / fmaxf((float)(end - beg), 1.0f);
        *(float4*)&mo[(size_t)node * 64 + q * 4] =
            make_float4(a0 * inv, a1 * inv, a2 * inv, a3 * inv);
    }
}

// ---- dual apply: out = relu?( mean @ wlT + self @ wrT + b ), in-place -----

__global__ __launch_bounds__(256) void apply_dual(
    int gm,
    float* __restrict__ xioM, const float* __restrict__ selfM,
    const float* __restrict__ wTlM, const float* __restrict__ wTrM,
    const float* __restrict__ blM, unsigned short* __restrict__ bfM, int M,
    float* __restrict__ xioU, const float* __restrict__ selfU,
    const float* __restrict__ wTlU, const float* __restrict__ wTrU,
    const float* __restrict__ blU, unsigned short* __restrict__ bfU, int U,
    int do_relu) {
    int b = blockIdx.x;
    float* xio; const float* self_; const float* wTl; const float* wTr;
    const float* bl; unsigned short* bf_out; int n;
    if (b < gm) { xio = xioM; self_ = selfM; wTl = wTlM; wTr = wTrM; bl = blM; bf_out = bfM; n = M; }
    else { b -= gm; xio = xioU; self_ = selfU; wTl = wTlU; wTr = wTrU; bl = blU; bf_out = bfU; n = U; }

    __shared__ float Xs[64 * 66];
    __shared__ float Ws[64 * 64];
    int tid = threadIdx.x;
    int node0 = b * 64;
    int hg = tid & 7, ng = tid >> 3;
    int h0 = hg * 8;
    int nA = ng * 2;

    float acc[2][8];
#pragma unroll
    for (int r = 0; r < 2; ++r)
#pragma unroll
        for (int c = 0; c < 8; ++c) acc[r][c] = 0.0f;

    for (int phase = 0; phase < 2; ++phase) {
        const float* X = phase ? self_ : xio;
        const float* W = phase ? wTr : wTl;
        __syncthreads();
        for (int i = tid; i < 4096; i += 256) {
            int nn = i >> 6, kk = i & 63;
            int gi = node0 + nn;
            Xs[nn * 66 + kk] = (gi < n) ? X[(size_t)gi * 64 + kk] : 0.0f;
            Ws[i] = W[i];
        }
        __syncthreads();
#pragma unroll 8
        for (int k = 0; k < 64; ++k) {
            float xa = Xs[nA * 66 + k];
            float xb = Xs[(nA + 1) * 66 + k];
            float4 w0 = *(const float4*)&Ws[k * 64 + h0];
            float4 w1 = *(const float4*)&Ws[k * 64 + h0 + 4];
            float w[8] = {w0.x, w0.y, w0.z, w0.w, w1.x, w1.y, w1.z, w1.w};
#pragma unroll
            for (int c = 0; c < 8; ++c) {
                acc[0][c] += xa * w[c];
                acc[1][c] += xb * w[c];
            }
        }
    }

    float4 b0 = *(const float4*)&bl[h0];
    float4 b1 = *(const float4*)&bl[h0 + 4];
    float bias[8] = {b0.x, b0.y, b0.z, b0.w, b1.x, b1.y, b1.z, b1.w};
#pragma unroll
    for (int r = 0; r < 2; ++r) {
        int gi = node0 + nA + r;
        if (gi < n) {
            float o[8];
#pragma unroll
            for (int c = 0; c < 8; ++c) {
                float v = acc[r][c] + bias[c];
                o[c] = do_relu ? fmaxf(v, 0.0f) : v;
            }
            *(float4*)&xio[(size_t)gi * 64 + h0]     = make_float4(o[0], o[1], o[2], o[3]);
            *(float4*)&xio[(size_t)gi * 64 + h0 + 4] = make_float4(o[4], o[5], o[6], o[7]);
            ushort4 p0, p1;
            p0.x = f2b(o[0]); p0.y = f2b(o[1]); p0.z = f2b(o[2]); p0.w = f2b(o[3]);
            p1.x = f2b(o[4]); p1.y = f2b(o[5]); p1.z = f2b(o[6]); p1.w = f2b(o[7]);
            *(ushort4*)&bf_out[(size_t)gi * 64 + h0]     = p0;
            *(ushort4*)&bf_out[(size_t)gi * 64 + h0 + 4] = p1;
        }
    }
}

// ---- link head: bf16 tables, 4 edges per wave (16 lanes each) -------------

__global__ __launch_bounds__(256) void dot_bf16(
    const int* __restrict__ ls, const int* __restrict__ ld,
    const unsigned short* __restrict__ xuB, const unsigned short* __restrict__ xmB,
    float* __restrict__ out, int L) {
    int t = blockIdx.x * 256 + threadIdx.x;
    int lane = t & 63;
    int sub = lane >> 4, q = lane & 15;
    int e = (t >> 6) * 4 + sub;
    if (e < L) {
        int u = ls[e], m = ld[e];
        ushort4 a = *(const ushort4*)(xuB + (size_t)u * 64 + q * 4);
        ushort4 b = *(const ushort4*)(xmB + (size_t)m * 64 + q * 4);
        float p = b2f(a.x) * b2f(b.x) + b2f(a.y) * b2f(b.y)
                + b2f(a.z) * b2f(b.z) + b2f(a.w) * b2f(b.w);
#pragma unroll
        for (int off = 1; off < 16; off <<= 1) p += __shfl_xor(p, off, 64);
        if (q == 0) out[e] = p;
    }
}

// ---------------------------------------------------------------------------

extern "C" void kernel_launch(void* const* d_in, const int* in_sizes, int n_in,
                              void* d_out, int out_size, void* d_ws, size_t ws_size,
                              hipStream_t stream) {
    const float* movie_x   = (const float*)d_in[0];
    const float* user_emb  = (const float*)d_in[1];
    const float* movie_emb = (const float*)d_in[2];
    const float* mlw       = (const float*)d_in[3];
    const float* mlb       = (const float*)d_in[4];
    const float* llw       = (const float*)d_in[5];   // [2][2][64][64]
    const float* llb       = (const float*)d_in[6];   // [2][2][64]
    const float* lrw       = (const float*)d_in[7];   // [2][2][64][64]
    const int*   esrc      = (const int*)d_in[8];
    const int*   edst      = (const int*)d_in[9];
    const int*   lsrc      = (const int*)d_in[10];
    const int*   ldst      = (const int*)d_in[11];

    const int U = in_sizes[1] / 64;
    const int M = in_sizes[2] / 64;
    const int E = in_sizes[8];
    const int L = in_sizes[10];
    float* out = (float*)d_out;

    const size_t M64 = (size_t)M * 64, U64 = (size_t)U * 64;
    const int nbu = (U + 255) >> 8;   // 256-user buckets
    const int nbm = (M + 127) >> 7;   // 128-movie buckets

    // ws layout (~113 MB):
    float* xm0 = (float*)d_ws;            // [M,64] init movie feat; L1 movie mean/out
    float* xm1 = xm0 + M64;               // [M,64] L0 movie mean/out
    float* xu1 = xm1 + M64;               // [U,64] L0 user mean/out (part_m alias)
    float* xu2 = xu1 + U64;               // [U,64] L1 user mean/out (part_u alias)
    float* wTl = xu2 + U64;               // [4][64][64]
    float* wTr = wTl + 4 * 4096;          // [4][64][64]
    unsigned short* bmB = (unsigned short*)(wTr + 4 * 4096);  // [M,64] bf16
    unsigned short* buB = bmB + M64;      // [U,64] bf16 (own region — no alias)
    int* rp_u  = (int*)(buB + U64);       // [U+1]
    int* rp_m  = rp_u + (U + 1);          // [M+1]
    int* col_u = rp_m + (M + 1);          // [E]
    int* col_m = col_u + E;               // [E]
    int* bcu   = col_m + E;               // [400] (contig with bcm for memset)
    int* bcm   = bcu + 400;               // [400]
    int* bpu   = bcm + 400;               // [401]
    int* bpm   = bpu + 401;               // [401]
    int* bfu   = bpm + 401;               // [400]
    int* bfm   = bfu + 400;               // [400]
    int2* part_m = (int2*)xu1;            // [E] int2 (16 MB <= 25.6 MB)
    int2* part_u = (int2*)xu2;            // [E] int2

    // ---- CSR build ----
    hipMemsetAsync(bcu, 0, 800 * sizeof(int), stream);
    coarse_hist<<<1024, 256, 0, stream>>>(esrc, edst, E, bcu, bcm, nbu, nbm);
    scan_dual<<<2, 512, 0, stream>>>(bcu, nbu, bpu, bfu, bcm, nbm, bpm, bfm, E);
    const int npart = (E + CH - 1) / CH;
    partition_both<<<npart, 256, 0, stream>>>(esrc, edst, E, nbu, nbm, bfu, bfm,
                                              part_u, part_m);
    fine_dual<<<nbm + nbu, 256, 0, stream>>>(nbm, part_m, bpm, rp_m, col_m, M,
                                             part_u, bpu, rp_u, col_u, U, E);

    // ---- node init + weights + bf16 user table ----
    movie_init_kernel<<<1024, 256, 0, stream>>>(movie_x, mlw, mlb, movie_emb, xm0, bmB, M);
    wt_kernel<<<64, 256, 0, stream>>>(llw, lrw, wTl, wTr);
    cvt_bf16<<<(U * 16 + 255) / 256, 256, 0, stream>>>(user_emb, buB, U * 16);

    const int gm_g = (M * 64 + 255) / 256, gu_g = (U * 64 + 255) / 256;
    const int gm_a = (M + 63) / 64,        gu_a = (U + 63) / 64;

    // ---- layer 0 ----
    gather_dual<<<gm_g + gu_g, 256, 0, stream>>>(gm_g,
        rp_m, col_m, buB, xm1, M,          // movie mean <- bu0
        rp_u, col_u, bmB, xu1, U);         // user mean <- bm0
    apply_dual<<<gm_a + gu_a, 256, 0, stream>>>(gm_a,
        xm1, xm0,      wTl + 0 * 4096, wTr + 0 * 4096, llb + 0 * 64, bmB, M,   // -> bm1
        xu1, user_emb, wTl + 1 * 4096, wTr + 1 * 4096, llb + 1 * 64, buB, U,   // -> bu1
        1);

    // ---- layer 1 ----
    gather_dual<<<gm_g + gu_g, 256, 0, stream>>>(gm_g,
        rp_m, col_m, buB, xm0, M,          // movie mean <- bu1
        rp_u, col_u, bmB, xu2, U);         // user mean <- bm1
    apply_dual<<<gm_a + gu_a, 256, 0, stream>>>(gm_a,
        xm0, xm1, wTl + 2 * 4096, wTr + 2 * 4096, llb + 2 * 64, bmB, M,        // -> final movie bf16
        xu2, xu1, wTl + 3 * 4096, wTr + 3 * 4096, llb + 3 * 64, buB, U,        // -> final user bf16
        0);

    // ---- link head (bf16 tables) ----
    dot_bf16<<<(L + 15) / 16, 256, 0, stream>>>(lsrc, ldst, buB, bmB, out, L);
}